// Round 1
// baseline (1347.383 us; speedup 1.0000x reference)
//
#include <hip/hip_runtime.h>
#include <hip/hip_bf16.h>
#include <cstdint>

#define IN_SZ 50000
#define NM 3
#define N0 40960
#define N1 16384
#define NB 4096
#define HD 256
#define DEG 16
#define E0 (N1*DEG)
#define E1 (NB*DEG)

// ---------------- threefry2x32 (JAX-exact) ----------------
__device__ __forceinline__ uint32_t rotl32(uint32_t x, uint32_t d){ return (x<<d)|(x>>(32u-d)); }

__device__ void tf2x32(uint32_t k0, uint32_t k1, uint32_t c0, uint32_t c1,
                       uint32_t& y0, uint32_t& y1)
{
  uint32_t ks2 = k0 ^ k1 ^ 0x1BD11BDAu;
  uint32_t x0 = c0 + k0, x1 = c1 + k1;
#define R4(a,b,c,d) \
  x0+=x1; x1=rotl32(x1,a); x1^=x0; \
  x0+=x1; x1=rotl32(x1,b); x1^=x0; \
  x0+=x1; x1=rotl32(x1,c); x1^=x0; \
  x0+=x1; x1=rotl32(x1,d); x1^=x0;
  R4(13,15,26,6)  x0+=k1;  x1+=ks2+1u;
  R4(17,29,16,24) x0+=ks2; x1+=k0+2u;
  R4(13,15,26,6)  x0+=k0;  x1+=k1+3u;
  R4(17,29,16,24) x0+=k1;  x1+=ks2+4u;
  R4(13,15,26,6)  x0+=ks2; x1+=k0+5u;
#undef R4
  y0=x0; y1=x1;
}

// coef[b][i] = scales_i * interp_mask[b][i]; also writes scales (3 floats) to out.
#define THREEFRY_PARTITIONABLE 1
__global__ void interp_coef_k(const float* __restrict__ masks, const float* __restrict__ sp,
                              float* __restrict__ coef, float* __restrict__ scales_out)
{
  int b = blockIdx.x*64 + threadIdx.x;
  if (b >= NB) return;
  // scales = softmax(scales_param)
  float s0=sp[0], s1=sp[1], s2=sp[2];
  float mx = fmaxf(s0,fmaxf(s1,s2));
  float e0=expf(s0-mx), e1=expf(s1-mx), e2=expf(s2-mx);
  float inv = 1.f/(e0+e1+e2);
  float sc[3] = {e0*inv, e1*inv, e2*inv};
  if (b == 0){ scales_out[0]=sc[0]; scales_out[1]=sc[1]; scales_out[2]=sc[2]; }

  uint32_t bits[3];
#if THREEFRY_PARTITIONABLE
  // split: key_j = threefry(base, (0, j)) full pair; lower bits use k2 (j=1)
  uint32_t K0,K1, t0,t1;
  tf2x32(0u,42u,0u,1u,K0,K1);
  for (int i=0;i<3;i++){
    uint32_t idx = (uint32_t)(b*3+i);
    tf2x32(K0,K1,0u,idx,t0,t1);
    bits[i] = (t0 ^ t1) & 1u;   // 32-bit bits = bits1 ^ bits2 (partitionable fold)
  }
#else
  // original path: split via iota(4) halves; random_bits via iota halves
  uint32_t a0,a1,c0,c1;
  tf2x32(0u,42u,0u,2u,a0,a1);
  tf2x32(0u,42u,1u,3u,c0,c1);
  uint32_t K0=a1, K1=c1; // k2 = second outputs
  for (int i=0;i<3;i++){
    uint32_t idx = (uint32_t)(b*3+i), y0,y1;
    const uint32_t half = (NB*NM)/2;
    if (idx < half){ tf2x32(K0,K1,idx,idx+half,y0,y1); bits[i]=y0&1u; }
    else { tf2x32(K0,K1,idx-half,idx,y0,y1); bits[i]=y1&1u; }
  }
#endif
  float mk[3] = {masks[b*3+0], masks[b*3+1], masks[b*3+2]};
  float msum = mk[0]+mk[1]+mk[2];
  float rs = (float)(bits[0]+bits[1]+bits[2]);
  float add = powf(1.f/(1.f+rs), 20.f) + powf(1.f/msum, 20.f);
  float lg[3]; float lmax = -1e30f;
  for (int i=0;i<3;i++){
    float rm = floorf((float)bits[i] + add);
    rm = rm/(rm+1e-10f);
    float mm = mk[i]*rm;
    lg[i] = mm + (1.f-mm)*(-1e10f);
    lmax = fmaxf(lmax, lg[i]);
  }
  float es[3], ssum=0.f;
  for (int i=0;i<3;i++){ es[i]=expf(lg[i]-lmax); ssum+=es[i]; }
  for (int i=0;i<3;i++) coef[b*3+i] = sc[i]*es[i]/ssum;
}

// ---------------- GEMM: C[m,o] = sum_k A[m,k]*W[o,k]  (A optionally gathered) --------
// Block: 256 thr, computes 64 rows x 256 cols. If ids: A[m,k] = preW[k*IN_SZ+ids[m]] + pre_b[k]
__global__ __launch_bounds__(256) void gemm_xw(
    const float* __restrict__ A, const int* __restrict__ ids, const float* __restrict__ pre_b,
    const float* __restrict__ W, float* __restrict__ C, int Mrows)
{
  __shared__ float aT[64][33];
  __shared__ float bT[32][257];
  __shared__ int sid[64];
  int t = threadIdx.x;
  int block_row = blockIdx.x * 64;
  if (ids && t < 64) sid[t] = ids[block_row + t];
  __syncthreads();

  int tx = t & 15, ty = t >> 4;
  float acc[4][16];
#pragma unroll
  for (int r=0;r<4;r++)
#pragma unroll
    for(int c=0;c<16;c++) acc[r][c]=0.f;

  for (int k0 = 0; k0 < 256; k0 += 32) {
    if (ids) {
      int row = t & 63;
      int kb = (t >> 6) * 8;
      int id = sid[row];
#pragma unroll
      for (int j=0;j<8;j++){
        int kk = kb + j;
        aT[row][kk] = A[(size_t)(k0+kk)*IN_SZ + id] + pre_b[k0+kk];
      }
    } else {
#pragma unroll
      for (int j=0;j<2;j++){
        int linear = j*256 + t;          // float4 index in 64x32 tile
        int row = linear >> 3;
        int kq = linear & 7;
        const float4 f = *reinterpret_cast<const float4*>(&A[(size_t)(block_row+row)*256 + k0 + kq*4]);
        aT[row][kq*4+0]=f.x; aT[row][kq*4+1]=f.y; aT[row][kq*4+2]=f.z; aT[row][kq*4+3]=f.w;
      }
    }
#pragma unroll
    for (int j=0;j<8;j++){
      int linear = j*256 + t;            // float4 index in 256x32 W tile
      int o = linear >> 3;
      int kq = linear & 7;
      const float4 f = *reinterpret_cast<const float4*>(&W[(size_t)o*256 + k0 + kq*4]);
      bT[kq*4+0][o]=f.x; bT[kq*4+1][o]=f.y; bT[kq*4+2][o]=f.z; bT[kq*4+3][o]=f.w;
    }
    __syncthreads();
#pragma unroll
    for (int kk=0; kk<32; kk++){
      float av[4];
#pragma unroll
      for(int r=0;r<4;r++) av[r] = aT[ty*4+r][kk];
#pragma unroll
      for(int c=0;c<16;c++){
        float bv = bT[kk][c*16 + tx];
#pragma unroll
        for(int r=0;r<4;r++) acc[r][c] = fmaf(av[r], bv, acc[r][c]);
      }
    }
    __syncthreads();
  }
#pragma unroll
  for(int r=0;r<4;r++){
    size_t row = (size_t)(block_row + ty*4 + r);
#pragma unroll
    for(int c=0;c<16;c++) C[row*256 + c*16 + tx] = acc[r][c];
  }
}

// ---------------- alpha[n,h] = sum_c xl[n,h*64+c]*att[h*64+c] ----------------
__global__ void alpha_k(const float* __restrict__ xl, const float* __restrict__ att,
                        float* __restrict__ alpha)
{
  int node = blockIdx.x;
  int t = threadIdx.x;
  float v = xl[(size_t)node*256 + t] * att[t];
#pragma unroll
  for (int off=32; off; off>>=1) v += __shfl_xor(v, off, 64);
  if ((t & 63) == 0) alpha[node*4 + (t>>6)] = v;
}

// ---------------- per-dst GAT message (16 contiguous edges/dst) ----------------
__global__ __launch_bounds__(256) void gat_msg(
    const float* __restrict__ xl, const float* __restrict__ alpha,
    const int* __restrict__ esrc, const float* __restrict__ bias,
    float* __restrict__ out)
{
  int d = blockIdx.x;
  int t = threadIdx.x;
  __shared__ int src[16];
  __shared__ float aw[16][4];
  if (t < 16) src[t] = esrc[d*16 + t];
  __syncthreads();
  if (t < 64) {
    int e = t & 15, h = t >> 4;
    float l = alpha[(size_t)src[e]*4 + h];
    aw[e][h] = l > 0.f ? l : 0.2f*l;   // leaky_relu 0.2
  }
  __syncthreads();
  if (t < 4) {
    int h = t;
    float m = -1e30f;
    for (int e=0;e<16;e++) m = fmaxf(m, aw[e][h]);
    float s = 0.f;
    for (int e=0;e<16;e++) s += expf(aw[e][h]-m);
    float invs = 1.f/(s + 1e-16f);
    for (int e=0;e<16;e++) aw[e][h] = expf(aw[e][h]-m)*invs;
  }
  __syncthreads();
  int h = t >> 6;
  float acc = 0.f;
#pragma unroll
  for (int e=0;e<16;e++) acc = fmaf(aw[e][h], xl[(size_t)src[e]*256 + t], acc);
  out[(size_t)d*256 + t] = acc + bias[t];
}

// ---------------- xmod accumulate ----------------
__global__ void accum_k(const float* __restrict__ g0, const float* __restrict__ g1,
                        const float* __restrict__ coef, int i, float* __restrict__ xmod)
{
  int g = blockIdx.x*256 + threadIdx.x;
  int b = g >> 8;
  float v = coef[b*3+i] * (2.f*g0[g] + 2.f*g1[g]);
  if (i == 0) xmod[g] = v; else xmod[g] += v;
}

// ---------------- emb_W transpose [128,256]->[256,128] ----------------
__global__ void transp_embW(const float* __restrict__ w, float* __restrict__ wt)
{
  int g = blockIdx.x*256 + threadIdx.x;   // 32768
  int j = g >> 8, k = g & 255;
  wt[k*128 + j] = w[g];
}

// ---------------- emb = xmod @ embW^T + b  (K=256, N=128) ----------------
__global__ __launch_bounds__(256) void emb_gemm(
  const float* __restrict__ xmod, const float* __restrict__ wT,
  const float* __restrict__ eb, float* __restrict__ emb)
{
  __shared__ float xs[32][260];
  int t = threadIdx.x;
  int brow = blockIdx.x * 32;
#pragma unroll
  for (int j=0;j<8;j++){
    int linear = j*256+t;                 // float4 idx, 64 per row
    int row = linear >> 6;
    int kq = linear & 63;
    float4 f = *reinterpret_cast<const float4*>(&xmod[(size_t)(brow+row)*256 + kq*4]);
    xs[row][kq*4+0]=f.x; xs[row][kq*4+1]=f.y; xs[row][kq*4+2]=f.z; xs[row][kq*4+3]=f.w;
  }
  __syncthreads();
  int tj = t & 127, th = t >> 7;
  float acc[16];
#pragma unroll
  for(int r=0;r<16;r++) acc[r]=0.f;
  for (int k=0;k<256;k++){
    float w = wT[k*128 + tj];
#pragma unroll
    for (int r=0;r<16;r++) acc[r] = fmaf(xs[th*16+r][k], w, acc[r]);
  }
  float bias = eb[tj];
#pragma unroll
  for (int r=0;r<16;r++) emb[(size_t)(brow+th*16+r)*128 + tj] = acc[r] + bias;
}

// ---------------- dot = emb @ emb^T  (4096x4096x128) ----------------
__global__ __launch_bounds__(256) void dot_gemm(const float* __restrict__ emb, float* __restrict__ dot)
{
  __shared__ float as[64][65], bs[64][65];
  int t = threadIdx.x;
  int tx = t & 15, ty = t >> 4;
  int arow = blockIdx.y*64, brow = blockIdx.x*64;
  float acc[4][4];
#pragma unroll
  for(int r=0;r<4;r++)
#pragma unroll
    for(int c=0;c<4;c++) acc[r][c]=0.f;

  for (int k0=0;k0<128;k0+=64){
#pragma unroll
    for (int j=0;j<4;j++){
      int linear = j*256+t;               // float4 idx, 16 per row
      int row = linear >> 4;
      int kq = linear & 15;
      float4 f = *reinterpret_cast<const float4*>(&emb[(size_t)(arow+row)*128 + k0 + kq*4]);
      as[row][kq*4+0]=f.x; as[row][kq*4+1]=f.y; as[row][kq*4+2]=f.z; as[row][kq*4+3]=f.w;
      float4 g = *reinterpret_cast<const float4*>(&emb[(size_t)(brow+row)*128 + k0 + kq*4]);
      bs[row][kq*4+0]=g.x; bs[row][kq*4+1]=g.y; bs[row][kq*4+2]=g.z; bs[row][kq*4+3]=g.w;
    }
    __syncthreads();
#pragma unroll
    for (int k=0;k<64;k++){
      float av[4], bv[4];
#pragma unroll
      for(int r=0;r<4;r++) av[r]=as[ty*4+r][k];
#pragma unroll
      for(int c=0;c<4;c++) bv[c]=bs[tx*4+c][k];
#pragma unroll
      for(int r=0;r<4;r++)
#pragma unroll
        for(int c=0;c<4;c++) acc[r][c] = fmaf(av[r], bv[c], acc[r][c]);
    }
    __syncthreads();
  }
#pragma unroll
  for(int r=0;r<4;r++){
    float4 o = make_float4(acc[r][0],acc[r][1],acc[r][2],acc[r][3]);
    *reinterpret_cast<float4*>(&dot[(size_t)(arow+ty*4+r)*4096 + brow + tx*4]) = o;
  }
}

extern "C" void kernel_launch(void* const* d_in, const int* in_sizes, int n_in,
                              void* d_out, int out_size, void* d_ws, size_t ws_size,
                              hipStream_t stream) {
  (void)in_sizes; (void)n_in; (void)out_size; (void)ws_size;
  const float* masks   = (const float*)d_in[0];
  const int*   n_ids   = (const int*)d_in[1];
  const int*   e0_src  = (const int*)d_in[2];
  const int*   e1_src  = (const int*)d_in[4];
  const float* pre_W   = (const float*)d_in[6];
  const float* pre_b   = (const float*)d_in[7];
  const float* gat_W   = (const float*)d_in[8];
  const float* gat_att = (const float*)d_in[9];
  const float* gat_b   = (const float*)d_in[10];
  const float* sp      = (const float*)d_in[11];
  const float* emb_W   = (const float*)d_in[12];
  const float* emb_b   = (const float*)d_in[13];

  float* out = (float*)d_out;
  float* dot = out;                        // [4096*4096]
  float* emb = out + (size_t)NB*NB;        // [4096*128]
  float* scales_out = emb + (size_t)NB*128;// [3]

  float* ws   = (float*)d_ws;
  float* xl   = ws;                        // N0*256 = 10485760 (reused as xl1)
  float* g0   = xl + (size_t)N0*256;       // N1*256 = 4194304
  float* g1   = g0 + (size_t)N1*256;       // NB*256 = 1048576
  float* xmod = g1 + (size_t)NB*256;       // 1048576
  float* alph = xmod + (size_t)NB*256;     // N0*4 = 163840
  float* coef = alph + (size_t)N0*4;       // NB*3 = 12288
  float* wT   = coef + NB*3;               // 32768

  interp_coef_k<<<64, 64, 0, stream>>>(masks, sp, coef, scales_out);
  transp_embW<<<128, 256, 0, stream>>>(emb_W, wT);

  for (int i = 0; i < NM; i++) {
    gemm_xw<<<N0/64, 256, 0, stream>>>(pre_W + (size_t)i*HD*IN_SZ, n_ids + (size_t)i*N0,
                                       pre_b + i*HD, gat_W + (size_t)i*HD*HD, xl, N0);
    alpha_k<<<N0, 256, 0, stream>>>(xl, gat_att + i*HD, alph);
    gat_msg<<<N1, 256, 0, stream>>>(xl, alph, e0_src + (size_t)i*E0, gat_b + i*HD, g0);
    gemm_xw<<<N1/64, 256, 0, stream>>>(g0, nullptr, nullptr, gat_W + (size_t)i*HD*HD, xl, N1);
    alpha_k<<<N1, 256, 0, stream>>>(xl, gat_att + i*HD, alph);
    gat_msg<<<NB, 256, 0, stream>>>(xl, alph, e1_src + (size_t)i*E1, gat_b + i*HD, g1);
    accum_k<<<NB, 256, 0, stream>>>(g0, g1, coef, i, xmod);
  }
  emb_gemm<<<NB/32, 256, 0, stream>>>(xmod, wT, emb_b, emb);
  dot_gemm<<<dim3(64,64), 256, 0, stream>>>(emb, dot);
}

// Round 2
// 906.220 us; speedup vs baseline: 1.4868x; 1.4868x over previous
//
#include <hip/hip_runtime.h>
#include <hip/hip_bf16.h>
#include <cstdint>

#define IN_SZ 50000
#define NM 3
#define N0 40960
#define N1 16384
#define NB 4096
#define HD 256
#define DEG 16
#define E0 (N1*DEG)
#define E1 (NB*DEG)

// ---------------- threefry2x32 (JAX-exact) ----------------
__device__ __forceinline__ uint32_t rotl32(uint32_t x, uint32_t d){ return (x<<d)|(x>>(32u-d)); }

__device__ void tf2x32(uint32_t k0, uint32_t k1, uint32_t c0, uint32_t c1,
                       uint32_t& y0, uint32_t& y1)
{
  uint32_t ks2 = k0 ^ k1 ^ 0x1BD11BDAu;
  uint32_t x0 = c0 + k0, x1 = c1 + k1;
#define R4(a,b,c,d) \
  x0+=x1; x1=rotl32(x1,a); x1^=x0; \
  x0+=x1; x1=rotl32(x1,b); x1^=x0; \
  x0+=x1; x1=rotl32(x1,c); x1^=x0; \
  x0+=x1; x1=rotl32(x1,d); x1^=x0;
  R4(13,15,26,6)  x0+=k1;  x1+=ks2+1u;
  R4(17,29,16,24) x0+=ks2; x1+=k0+2u;
  R4(13,15,26,6)  x0+=k0;  x1+=k1+3u;
  R4(17,29,16,24) x0+=k1;  x1+=ks2+4u;
  R4(13,15,26,6)  x0+=ks2; x1+=k0+5u;
#undef R4
  y0=x0; y1=x1;
}

__global__ void interp_coef_k(const float* __restrict__ masks, const float* __restrict__ sp,
                              float* __restrict__ coef, float* __restrict__ scales_out)
{
  int b = blockIdx.x*64 + threadIdx.x;
  if (b >= NB) return;
  float s0=sp[0], s1=sp[1], s2=sp[2];
  float mx = fmaxf(s0,fmaxf(s1,s2));
  float e0=expf(s0-mx), e1=expf(s1-mx), e2=expf(s2-mx);
  float inv = 1.f/(e0+e1+e2);
  float sc[3] = {e0*inv, e1*inv, e2*inv};
  if (b == 0){ scales_out[0]=sc[0]; scales_out[1]=sc[1]; scales_out[2]=sc[2]; }

  uint32_t bits[3];
  uint32_t K0,K1, t0,t1;
  tf2x32(0u,42u,0u,1u,K0,K1);
  for (int i=0;i<3;i++){
    uint32_t idx = (uint32_t)(b*3+i);
    tf2x32(K0,K1,0u,idx,t0,t1);
    bits[i] = (t0 ^ t1) & 1u;
  }
  float mk[3] = {masks[b*3+0], masks[b*3+1], masks[b*3+2]};
  float msum = mk[0]+mk[1]+mk[2];
  float rs = (float)(bits[0]+bits[1]+bits[2]);
  float add = powf(1.f/(1.f+rs), 20.f) + powf(1.f/msum, 20.f);
  float lg[3]; float lmax = -1e30f;
  for (int i=0;i<3;i++){
    float rm = floorf((float)bits[i] + add);
    rm = rm/(rm+1e-10f);
    float mm = mk[i]*rm;
    lg[i] = mm + (1.f-mm)*(-1e10f);
    lmax = fmaxf(lmax, lg[i]);
  }
  float es[3], ssum=0.f;
  for (int i=0;i<3;i++){ es[i]=expf(lg[i]-lmax); ssum+=es[i]; }
  for (int i=0;i<3;i++) coef[b*3+i] = sc[i]*es[i]/ssum;
}

// ---------------- transpose pre_W [256, 50000] -> WTb [50000, 256], bias baked ----
__global__ __launch_bounds__(256) void transp_k(const float* __restrict__ W,
                                                const float* __restrict__ bvec,
                                                float* __restrict__ WT)
{
  __shared__ float tile[32][33];
  int c0 = blockIdx.x*32, k0 = blockIdx.y*32;
  int tx = threadIdx.x & 31, tg = threadIdx.x >> 5;  // 8 groups of 32
#pragma unroll
  for (int j=0;j<4;j++){
    int k = k0 + tg*4 + j;
    int c = c0 + tx;
    tile[tg*4+j][tx] = (c < IN_SZ) ? W[(size_t)k*IN_SZ + c] : 0.f;
  }
  __syncthreads();
#pragma unroll
  for (int j=0;j<4;j++){
    int c = c0 + tg*4 + j;
    int k = k0 + tx;
    if (c < IN_SZ) WT[(size_t)c*HD + k] = tile[tx][tg*4+j] + bvec[k];
  }
}

// ---------------- GEMM: C[m,o] = sum_k A[rowsel(m),k]*W[o,k]; fused alpha epilogue ---
// A is [*,256] row-major; if ids, row = ids[m] else row = m.
__global__ __launch_bounds__(256) void gemm_xw(
    const float* __restrict__ A, const int* __restrict__ ids,
    const float* __restrict__ W, float* __restrict__ C,
    const float* __restrict__ att, float* __restrict__ alpha)
{
  __shared__ float aT[64][33];
  __shared__ float bT[32][257];
  __shared__ int sid[64];
  int t = threadIdx.x;
  int block_row = blockIdx.x * 64;
  if (ids && t < 64) sid[t] = ids[block_row + t];
  __syncthreads();

  int tx = t & 15, ty = t >> 4;
  float acc[4][16];
#pragma unroll
  for (int r=0;r<4;r++)
#pragma unroll
    for(int c=0;c<16;c++) acc[r][c]=0.f;

  for (int k0 = 0; k0 < 256; k0 += 32) {
#pragma unroll
    for (int j=0;j<2;j++){
      int linear = j*256 + t;            // float4 idx over 64x32 tile
      int row = linear >> 3;
      int kq = linear & 7;
      size_t rbase = ids ? (size_t)sid[row]*HD : (size_t)(block_row+row)*HD;
      const float4 f = *reinterpret_cast<const float4*>(&A[rbase + k0 + kq*4]);
      aT[row][kq*4+0]=f.x; aT[row][kq*4+1]=f.y; aT[row][kq*4+2]=f.z; aT[row][kq*4+3]=f.w;
    }
#pragma unroll
    for (int j=0;j<8;j++){
      int linear = j*256 + t;            // float4 idx over 256x32 W tile
      int o = linear >> 3;
      int kq = linear & 7;
      const float4 f = *reinterpret_cast<const float4*>(&W[(size_t)o*256 + k0 + kq*4]);
      bT[kq*4+0][o]=f.x; bT[kq*4+1][o]=f.y; bT[kq*4+2][o]=f.z; bT[kq*4+3][o]=f.w;
    }
    __syncthreads();
#pragma unroll
    for (int kk=0; kk<32; kk++){
      float av[4];
#pragma unroll
      for(int r=0;r<4;r++) av[r] = aT[ty*4+r][kk];
#pragma unroll
      for(int c=0;c<16;c++){
        float bv = bT[kk][c*16 + tx];
#pragma unroll
        for(int r=0;r<4;r++) acc[r][c] = fmaf(av[r], bv, acc[r][c]);
      }
    }
    __syncthreads();
  }
  // store C + fused alpha[n,h] = sum_c C[n, h*64+c]*att[h*64+c]
  float attv[16];
#pragma unroll
  for (int c=0;c<16;c++) attv[c] = att[c*16+tx];
#pragma unroll
  for(int r=0;r<4;r++){
    size_t row = (size_t)(block_row + ty*4 + r);
#pragma unroll
    for(int c=0;c<16;c++) C[row*256 + c*16 + tx] = acc[r][c];
#pragma unroll
    for(int h=0;h<4;h++){
      float p = 0.f;
#pragma unroll
      for(int j=0;j<4;j++) p = fmaf(acc[r][4*h+j], attv[4*h+j], p);
      p += __shfl_xor(p, 1, 64);
      p += __shfl_xor(p, 2, 64);
      p += __shfl_xor(p, 4, 64);
      p += __shfl_xor(p, 8, 64);
      if (tx == 0) alpha[row*4 + h] = p;
    }
  }
}

// ---------------- layer-0 GAT message: out[d] = sum_e a[e,h]*xl[src] + bias ------
__global__ __launch_bounds__(256) void gat_msg0(
    const float* __restrict__ xl, const float* __restrict__ alpha,
    const int* __restrict__ esrc, const float* __restrict__ bias,
    float* __restrict__ out)
{
  int d = blockIdx.x;
  int t = threadIdx.x;
  __shared__ int src[16];
  __shared__ float aw[16][4];
  if (t < 16) src[t] = esrc[d*16 + t];
  __syncthreads();
  if (t < 64) {
    int e = t & 15, h = t >> 4;
    float l = alpha[(size_t)src[e]*4 + h];
    l = l > 0.f ? l : 0.2f*l;
    float m = l;
#pragma unroll
    for (int off=1; off<16; off<<=1) m = fmaxf(m, __shfl_xor(m, off, 64));
    float ex = expf(l - m);
    float s = ex;
#pragma unroll
    for (int off=1; off<16; off<<=1) s += __shfl_xor(s, off, 64);
    aw[e][h] = ex / (s + 1e-16f);
  }
  __syncthreads();
  int h = t >> 6;
  float acc = 0.f;
#pragma unroll
  for (int e=0;e<16;e++) acc = fmaf(aw[e][h], xl[(size_t)src[e]*256 + t], acc);
  out[(size_t)d*256 + t] = acc + bias[t];
}

// ---------------- layer-1 GAT message, fused gating accumulate into xmod ---------
__global__ __launch_bounds__(256) void gat_msg1(
    const float* __restrict__ xl, const float* __restrict__ alpha,
    const int* __restrict__ esrc, const float* __restrict__ bias,
    const float* __restrict__ g0, const float* __restrict__ coef, int i,
    float* __restrict__ xmod)
{
  int d = blockIdx.x;
  int t = threadIdx.x;
  __shared__ int src[16];
  __shared__ float aw[16][4];
  if (t < 16) src[t] = esrc[d*16 + t];
  __syncthreads();
  if (t < 64) {
    int e = t & 15, h = t >> 4;
    float l = alpha[(size_t)src[e]*4 + h];
    l = l > 0.f ? l : 0.2f*l;
    float m = l;
#pragma unroll
    for (int off=1; off<16; off<<=1) m = fmaxf(m, __shfl_xor(m, off, 64));
    float ex = expf(l - m);
    float s = ex;
#pragma unroll
    for (int off=1; off<16; off<<=1) s += __shfl_xor(s, off, 64);
    aw[e][h] = ex / (s + 1e-16f);
  }
  __syncthreads();
  int h = t >> 6;
  float acc = 0.f;
#pragma unroll
  for (int e=0;e<16;e++) acc = fmaf(aw[e][h], xl[(size_t)src[e]*256 + t], acc);
  float cv = coef[d*3 + i];
  float v = cv * (2.f*g0[(size_t)d*256 + t] + 2.f*(acc + bias[t]));
  size_t g = (size_t)d*256 + t;
  if (i == 0) xmod[g] = v; else xmod[g] += v;
}

// ---------------- emb_W transpose [128,256]->[256,128] ----------------
__global__ void transp_embW(const float* __restrict__ w, float* __restrict__ wt)
{
  int g = blockIdx.x*256 + threadIdx.x;
  int j = g >> 8, k = g & 255;
  wt[k*128 + j] = w[g];
}

// ---------------- emb = xmod @ embW^T + b  (K=256, N=128) ----------------
__global__ __launch_bounds__(256) void emb_gemm(
  const float* __restrict__ xmod, const float* __restrict__ wT,
  const float* __restrict__ eb, float* __restrict__ emb)
{
  __shared__ float xs[32][260];
  int t = threadIdx.x;
  int brow = blockIdx.x * 32;
#pragma unroll
  for (int j=0;j<8;j++){
    int linear = j*256+t;
    int row = linear >> 6;
    int kq = linear & 63;
    float4 f = *reinterpret_cast<const float4*>(&xmod[(size_t)(brow+row)*256 + kq*4]);
    xs[row][kq*4+0]=f.x; xs[row][kq*4+1]=f.y; xs[row][kq*4+2]=f.z; xs[row][kq*4+3]=f.w;
  }
  __syncthreads();
  int tj = t & 127, th = t >> 7;
  float acc[16];
#pragma unroll
  for(int r=0;r<16;r++) acc[r]=0.f;
  for (int k=0;k<256;k++){
    float w = wT[k*128 + tj];
#pragma unroll
    for (int r=0;r<16;r++) acc[r] = fmaf(xs[th*16+r][k], w, acc[r]);
  }
  float bias = eb[tj];
#pragma unroll
  for (int r=0;r<16;r++) emb[(size_t)(brow+th*16+r)*128 + tj] = acc[r] + bias;
}

// ---------------- dot = emb @ emb^T  (4096x4096x128) ----------------
__global__ __launch_bounds__(256) void dot_gemm(const float* __restrict__ emb, float* __restrict__ dot)
{
  __shared__ float as[64][65], bs[64][65];
  int t = threadIdx.x;
  int tx = t & 15, ty = t >> 4;
  int arow = blockIdx.y*64, brow = blockIdx.x*64;
  float acc[4][4];
#pragma unroll
  for(int r=0;r<4;r++)
#pragma unroll
    for(int c=0;c<4;c++) acc[r][c]=0.f;

  for (int k0=0;k0<128;k0+=64){
#pragma unroll
    for (int j=0;j<4;j++){
      int linear = j*256+t;
      int row = linear >> 4;
      int kq = linear & 15;
      float4 f = *reinterpret_cast<const float4*>(&emb[(size_t)(arow+row)*128 + k0 + kq*4]);
      as[row][kq*4+0]=f.x; as[row][kq*4+1]=f.y; as[row][kq*4+2]=f.z; as[row][kq*4+3]=f.w;
      float4 g = *reinterpret_cast<const float4*>(&emb[(size_t)(brow+row)*128 + k0 + kq*4]);
      bs[row][kq*4+0]=g.x; bs[row][kq*4+1]=g.y; bs[row][kq*4+2]=g.z; bs[row][kq*4+3]=g.w;
    }
    __syncthreads();
#pragma unroll
    for (int k=0;k<64;k++){
      float av[4], bv[4];
#pragma unroll
      for(int r=0;r<4;r++) av[r]=as[ty*4+r][k];
#pragma unroll
      for(int c=0;c<4;c++) bv[c]=bs[tx*4+c][k];
#pragma unroll
      for(int r=0;r<4;r++)
#pragma unroll
        for(int c=0;c<4;c++) acc[r][c] = fmaf(av[r], bv[c], acc[r][c]);
    }
    __syncthreads();
  }
#pragma unroll
  for(int r=0;r<4;r++){
    float4 o = make_float4(acc[r][0],acc[r][1],acc[r][2],acc[r][3]);
    *reinterpret_cast<float4*>(&dot[(size_t)(arow+ty*4+r)*4096 + brow + tx*4]) = o;
  }
}

extern "C" void kernel_launch(void* const* d_in, const int* in_sizes, int n_in,
                              void* d_out, int out_size, void* d_ws, size_t ws_size,
                              hipStream_t stream) {
  (void)in_sizes; (void)n_in; (void)out_size; (void)ws_size;
  const float* masks   = (const float*)d_in[0];
  const int*   n_ids   = (const int*)d_in[1];
  const int*   e0_src  = (const int*)d_in[2];
  const int*   e1_src  = (const int*)d_in[4];
  const float* pre_W   = (const float*)d_in[6];
  const float* pre_b   = (const float*)d_in[7];
  const float* gat_W   = (const float*)d_in[8];
  const float* gat_att = (const float*)d_in[9];
  const float* gat_b   = (const float*)d_in[10];
  const float* sp      = (const float*)d_in[11];
  const float* emb_W   = (const float*)d_in[12];
  const float* emb_b   = (const float*)d_in[13];

  float* out = (float*)d_out;
  float* dot = out;                         // [4096*4096]
  float* emb = out + (size_t)NB*NB;         // [4096*128]
  float* scales_out = emb + (size_t)NB*128; // [3]

  float* ws   = (float*)d_ws;
  float* WTb  = ws;                         // 50000*256 = 12.8M floats
  float* xl   = WTb + (size_t)IN_SZ*HD;     // 40960*256
  float* g0   = xl + (size_t)N0*HD;         // 16384*256
  float* xmod = g0 + (size_t)N1*HD;         // 4096*256
  float* alph = xmod + (size_t)NB*HD;       // 40960*4
  float* coef = alph + (size_t)N0*4;        // 4096*3
  float* wT   = coef + NB*3;                // 32768

  interp_coef_k<<<64, 64, 0, stream>>>(masks, sp, coef, scales_out);
  transp_embW<<<128, 256, 0, stream>>>(emb_W, wT);

  for (int i = 0; i < NM; i++) {
    transp_k<<<dim3((IN_SZ+31)/32, 8), 256, 0, stream>>>(
        pre_W + (size_t)i*HD*IN_SZ, pre_b + i*HD, WTb);
    gemm_xw<<<N0/64, 256, 0, stream>>>(WTb, n_ids + (size_t)i*N0,
                                       gat_W + (size_t)i*HD*HD, xl,
                                       gat_att + i*HD, alph);
    gat_msg0<<<N1, 256, 0, stream>>>(xl, alph, e0_src + (size_t)i*E0, gat_b + i*HD, g0);
    gemm_xw<<<N1/64, 256, 0, stream>>>(g0, nullptr,
                                       gat_W + (size_t)i*HD*HD, xl,
                                       gat_att + i*HD, alph);
    gat_msg1<<<NB, 256, 0, stream>>>(xl, alph, e1_src + (size_t)i*E1, gat_b + i*HD,
                                     g0, coef, i, xmod);
  }
  emb_gemm<<<NB/32, 256, 0, stream>>>(xmod, wT, emb_b, emb);
  dot_gemm<<<dim3(64,64), 256, 0, stream>>>(emb, dot);
}

// Round 3
// 523.871 us; speedup vs baseline: 2.5720x; 1.7299x over previous
//
#include <hip/hip_runtime.h>
#include <hip/hip_bf16.h>
#include <cstdint>

#define IN_SZ 50000
#define NM 3
#define N0 40960
#define N1 16384
#define NB 4096
#define HD 256
#define DEG 16
#define E0 (N1*DEG)
#define E1 (NB*DEG)

using short8v = __attribute__((ext_vector_type(8))) short;
using floatx4 = __attribute__((ext_vector_type(4))) float;

__device__ __forceinline__ unsigned short f2bf(float f){
  uint32_t u = __float_as_uint(f);
  uint32_t r = u + 0x7FFFu + ((u>>16)&1u);
  return (unsigned short)(r>>16);
}
__device__ __forceinline__ float bf2f(unsigned short h){
  return __uint_as_float(((uint32_t)h)<<16);
}

// ---------------- threefry2x32 (JAX-exact) ----------------
__device__ __forceinline__ uint32_t rotl32(uint32_t x, uint32_t d){ return (x<<d)|(x>>(32u-d)); }

__device__ void tf2x32(uint32_t k0, uint32_t k1, uint32_t c0, uint32_t c1,
                       uint32_t& y0, uint32_t& y1)
{
  uint32_t ks2 = k0 ^ k1 ^ 0x1BD11BDAu;
  uint32_t x0 = c0 + k0, x1 = c1 + k1;
#define R4(a,b,c,d) \
  x0+=x1; x1=rotl32(x1,a); x1^=x0; \
  x0+=x1; x1=rotl32(x1,b); x1^=x0; \
  x0+=x1; x1=rotl32(x1,c); x1^=x0; \
  x0+=x1; x1=rotl32(x1,d); x1^=x0;
  R4(13,15,26,6)  x0+=k1;  x1+=ks2+1u;
  R4(17,29,16,24) x0+=ks2; x1+=k0+2u;
  R4(13,15,26,6)  x0+=k0;  x1+=k1+3u;
  R4(17,29,16,24) x0+=k1;  x1+=ks2+4u;
  R4(13,15,26,6)  x0+=ks2; x1+=k0+5u;
#undef R4
  y0=x0; y1=x1;
}

__global__ void interp_coef_k(const float* __restrict__ masks, const float* __restrict__ sp,
                              float* __restrict__ coef, float* __restrict__ scales_out)
{
  int b = blockIdx.x*64 + threadIdx.x;
  if (b >= NB) return;
  float s0=sp[0], s1=sp[1], s2=sp[2];
  float mx = fmaxf(s0,fmaxf(s1,s2));
  float e0=expf(s0-mx), e1=expf(s1-mx), e2=expf(s2-mx);
  float inv = 1.f/(e0+e1+e2);
  float sc[3] = {e0*inv, e1*inv, e2*inv};
  if (b == 0){ scales_out[0]=sc[0]; scales_out[1]=sc[1]; scales_out[2]=sc[2]; }

  uint32_t bits[3];
  uint32_t K0,K1, t0,t1;
  tf2x32(0u,42u,0u,1u,K0,K1);
  for (int i=0;i<3;i++){
    uint32_t idx = (uint32_t)(b*3+i);
    tf2x32(K0,K1,0u,idx,t0,t1);
    bits[i] = (t0 ^ t1) & 1u;
  }
  float mk[3] = {masks[b*3+0], masks[b*3+1], masks[b*3+2]};
  float msum = mk[0]+mk[1]+mk[2];
  float rs = (float)(bits[0]+bits[1]+bits[2]);
  float add = powf(1.f/(1.f+rs), 20.f) + powf(1.f/msum, 20.f);
  float lg[3]; float lmax = -1e30f;
  for (int i=0;i<3;i++){
    float rm = floorf((float)bits[i] + add);
    rm = rm/(rm+1e-10f);
    float mm = mk[i]*rm;
    lg[i] = mm + (1.f-mm)*(-1e10f);
    lmax = fmaxf(lmax, lg[i]);
  }
  float es[3], ssum=0.f;
  for (int i=0;i<3;i++){ es[i]=expf(lg[i]-lmax); ssum+=es[i]; }
  for (int i=0;i<3;i++) coef[b*3+i] = sc[i]*es[i]/ssum;
}

// ---------------- transpose+split pre_W [256,50000] -> WThi/WTlo [50000,256] bf16, bias baked
__global__ __launch_bounds__(256) void transp_split_k(const float* __restrict__ W,
                                                      const float* __restrict__ bvec,
                                                      unsigned short* __restrict__ WThi,
                                                      unsigned short* __restrict__ WTlo)
{
  __shared__ float tile[32][33];
  int c0 = blockIdx.x*32, k0 = blockIdx.y*32;
  int tx = threadIdx.x & 31, tg = threadIdx.x >> 5;
#pragma unroll
  for (int j=0;j<4;j++){
    int k = k0 + tg*4 + j;
    int c = c0 + tx;
    tile[tg*4+j][tx] = (c < IN_SZ) ? W[(size_t)k*IN_SZ + c] : 0.f;
  }
  __syncthreads();
#pragma unroll
  for (int j=0;j<4;j++){
    int c = c0 + tg*4 + j;
    int k = k0 + tx;
    if (c < IN_SZ){
      float v = tile[tx][tg*4+j] + bvec[k];
      unsigned short h = f2bf(v);
      WThi[(size_t)c*HD + k] = h;
      WTlo[(size_t)c*HD + k] = f2bf(v - bf2f(h));
    }
  }
}

// ---------------- elementwise hi/lo split (gat_W, all modalities at once) -------
__global__ void split_k(const float* __restrict__ src, unsigned short* __restrict__ hi,
                        unsigned short* __restrict__ lo, int n)
{
  int g = blockIdx.x*256 + threadIdx.x;
  if (g >= n) return;
  float v = src[g];
  unsigned short h = f2bf(v);
  hi[g] = h;
  lo[g] = f2bf(v - bf2f(h));
}

// ---------------- MFMA GEMM: C[m,o]=sum_k A[row(m),k]*W[o,k], 3-term bf16 split ----
// BM=64 (4 waves x 16 rows), BN=256 (16 col-tiles), K=256 in chunks of 32.
// Fused alpha epilogue: alpha[n,h] = sum_c C[n,h*64+c]*att[h*64+c].
template<bool HAS_IDS>
__global__ __launch_bounds__(256) void gemm_mfma(
    const unsigned short* __restrict__ Ahi, const unsigned short* __restrict__ Alo,
    const int* __restrict__ ids,
    const unsigned short* __restrict__ Whi, const unsigned short* __restrict__ Wlo,
    float* __restrict__ C, const float* __restrict__ att, float* __restrict__ alpha)
{
  __shared__ __align__(16) unsigned short lbh[8192];  // [ot16][lane64][8] fragment-ordered
  __shared__ __align__(16) unsigned short lbl[8192];
  __shared__ int sid[64];
  int t = threadIdx.x;
  int wave = t>>6, lane = t&63;
  int block_row = blockIdx.x*64;
  if (HAS_IDS && t < 64) sid[t] = ids[block_row + t];
  __syncthreads();

  int arow;
  if (HAS_IDS) arow = sid[wave*16 + (lane&15)];
  else         arow = block_row + wave*16 + (lane&15);
  const unsigned short* aphi = Ahi + (size_t)arow*HD + ((lane>>4)*8);
  const unsigned short* aplo = Alo + (size_t)arow*HD + ((lane>>4)*8);

  floatx4 acc[16];
#pragma unroll
  for (int i=0;i<16;i++) acc[i] = (floatx4){0.f,0.f,0.f,0.f};

  const int o = t;  // staging: thread t owns W row o
  for (int k0=0; k0<256; k0+=32){
    // reg-stage W chunk + A frags (global loads before barrier)
    short8v wh[4], wl[4];
#pragma unroll
    for (int g=0; g<4; g++){
      wh[g] = *reinterpret_cast<const short8v*>(Whi + (size_t)o*HD + k0 + g*8);
      wl[g] = *reinterpret_cast<const short8v*>(Wlo + (size_t)o*HD + k0 + g*8);
    }
    short8v ah = *reinterpret_cast<const short8v*>(aphi + k0);
    short8v al = *reinterpret_cast<const short8v*>(aplo + k0);
    __syncthreads();   // previous chunk's compute done before overwrite
#pragma unroll
    for (int g=0; g<4; g++){
      int idx = (o>>4)*512 + ((g<<4)|(o&15))*8;   // [ot][lane][8]
      *reinterpret_cast<short8v*>(&lbh[idx]) = wh[g];
      *reinterpret_cast<short8v*>(&lbl[idx]) = wl[g];
    }
    __syncthreads();
#pragma unroll
    for (int ot=0; ot<16; ot++){
      short8v bh = *reinterpret_cast<const short8v*>(&lbh[ot*512 + lane*8]);
      short8v bl = *reinterpret_cast<const short8v*>(&lbl[ot*512 + lane*8]);
      acc[ot] = __builtin_amdgcn_mfma_f32_16x16x32_bf16(ah, bh, acc[ot], 0, 0, 0);
      acc[ot] = __builtin_amdgcn_mfma_f32_16x16x32_bf16(ah, bl, acc[ot], 0, 0, 0);
      acc[ot] = __builtin_amdgcn_mfma_f32_16x16x32_bf16(al, bh, acc[ot], 0, 0, 0);
    }
  }

  // epilogue: store C + fused alpha
  float attv[16];
#pragma unroll
  for (int ot=0; ot<16; ot++) attv[ot] = att[ot*16 + (lane&15)];
  int rbase = block_row + wave*16 + (lane>>4)*4;
#pragma unroll
  for (int r=0; r<4; r++){
    size_t row = (size_t)(rbase + r);
#pragma unroll
    for (int ot=0; ot<16; ot++) C[row*HD + ot*16 + (lane&15)] = acc[ot][r];
#pragma unroll
    for (int h=0; h<4; h++){
      float p = acc[4*h+0][r]*attv[4*h+0] + acc[4*h+1][r]*attv[4*h+1]
              + acc[4*h+2][r]*attv[4*h+2] + acc[4*h+3][r]*attv[4*h+3];
      p += __shfl_xor(p, 1, 64);
      p += __shfl_xor(p, 2, 64);
      p += __shfl_xor(p, 4, 64);
      p += __shfl_xor(p, 8, 64);
      if ((lane&15) == 0) alpha[row*4 + h] = p;
    }
  }
}

// ---------------- layer-0 GAT message; writes fp32 + bf16 hi/lo ------------------
__global__ __launch_bounds__(256) void gat_msg0(
    const float* __restrict__ xl, const float* __restrict__ alpha,
    const int* __restrict__ esrc, const float* __restrict__ bias,
    float* __restrict__ out, unsigned short* __restrict__ outhi,
    unsigned short* __restrict__ outlo)
{
  int d = blockIdx.x;
  int t = threadIdx.x;
  __shared__ int src[16];
  __shared__ float aw[16][4];
  if (t < 16) src[t] = esrc[d*16 + t];
  __syncthreads();
  if (t < 64) {
    int e = t & 15, h = t >> 4;
    float l = alpha[(size_t)src[e]*4 + h];
    l = l > 0.f ? l : 0.2f*l;
    float m = l;
#pragma unroll
    for (int off=1; off<16; off<<=1) m = fmaxf(m, __shfl_xor(m, off, 64));
    float ex = expf(l - m);
    float s = ex;
#pragma unroll
    for (int off=1; off<16; off<<=1) s += __shfl_xor(s, off, 64);
    aw[e][h] = ex / (s + 1e-16f);
  }
  __syncthreads();
  int h = t >> 6;
  float acc = 0.f;
#pragma unroll
  for (int e=0;e<16;e++) acc = fmaf(aw[e][h], xl[(size_t)src[e]*256 + t], acc);
  float v = acc + bias[t];
  size_t g = (size_t)d*256 + t;
  out[g] = v;
  unsigned short hb = f2bf(v);
  outhi[g] = hb;
  outlo[g] = f2bf(v - bf2f(hb));
}

// ---------------- layer-1 GAT message, fused gating accumulate into xmod ---------
__global__ __launch_bounds__(256) void gat_msg1(
    const float* __restrict__ xl, const float* __restrict__ alpha,
    const int* __restrict__ esrc, const float* __restrict__ bias,
    const float* __restrict__ g0, const float* __restrict__ coef, int i,
    float* __restrict__ xmod)
{
  int d = blockIdx.x;
  int t = threadIdx.x;
  __shared__ int src[16];
  __shared__ float aw[16][4];
  if (t < 16) src[t] = esrc[d*16 + t];
  __syncthreads();
  if (t < 64) {
    int e = t & 15, h = t >> 4;
    float l = alpha[(size_t)src[e]*4 + h];
    l = l > 0.f ? l : 0.2f*l;
    float m = l;
#pragma unroll
    for (int off=1; off<16; off<<=1) m = fmaxf(m, __shfl_xor(m, off, 64));
    float ex = expf(l - m);
    float s = ex;
#pragma unroll
    for (int off=1; off<16; off<<=1) s += __shfl_xor(s, off, 64);
    aw[e][h] = ex / (s + 1e-16f);
  }
  __syncthreads();
  int h = t >> 6;
  float acc = 0.f;
#pragma unroll
  for (int e=0;e<16;e++) acc = fmaf(aw[e][h], xl[(size_t)src[e]*256 + t], acc);
  float cv = coef[d*3 + i];
  float v = cv * (2.f*g0[(size_t)d*256 + t] + 2.f*(acc + bias[t]));
  size_t g = (size_t)d*256 + t;
  if (i == 0) xmod[g] = v; else xmod[g] += v;
}

// ---------------- emb_W transpose [128,256]->[256,128] ----------------
__global__ void transp_embW(const float* __restrict__ w, float* __restrict__ wt)
{
  int g = blockIdx.x*256 + threadIdx.x;
  int j = g >> 8, k = g & 255;
  wt[k*128 + j] = w[g];
}

// ---------------- emb = xmod @ embW^T + b; writes fp32 + hi/lo bf16 --------------
__global__ __launch_bounds__(256) void emb_gemm(
  const float* __restrict__ xmod, const float* __restrict__ wT,
  const float* __restrict__ eb, float* __restrict__ emb,
  unsigned short* __restrict__ ehi, unsigned short* __restrict__ elo)
{
  __shared__ float xs[32][260];
  int t = threadIdx.x;
  int brow = blockIdx.x * 32;
#pragma unroll
  for (int j=0;j<8;j++){
    int linear = j*256+t;
    int row = linear >> 6;
    int kq = linear & 63;
    float4 f = *reinterpret_cast<const float4*>(&xmod[(size_t)(brow+row)*256 + kq*4]);
    xs[row][kq*4+0]=f.x; xs[row][kq*4+1]=f.y; xs[row][kq*4+2]=f.z; xs[row][kq*4+3]=f.w;
  }
  __syncthreads();
  int tj = t & 127, th = t >> 7;
  float acc[16];
#pragma unroll
  for(int r=0;r<16;r++) acc[r]=0.f;
  for (int k=0;k<256;k++){
    float w = wT[k*128 + tj];
#pragma unroll
    for (int r=0;r<16;r++) acc[r] = fmaf(xs[th*16+r][k], w, acc[r]);
  }
  float bias = eb[tj];
#pragma unroll
  for (int r=0;r<16;r++){
    size_t idx = (size_t)(brow+th*16+r)*128 + tj;
    float v = acc[r] + bias;
    emb[idx] = v;
    unsigned short hb = f2bf(v);
    ehi[idx] = hb;
    elo[idx] = f2bf(v - bf2f(hb));
  }
}

// ---------------- dot = emb @ emb^T via MFMA, 3-term split -----------------------
// BM=BN=128, K=128. 4 waves: wave w rows 32w..32w+31 (2 row-tiles), 8 col-tiles.
__global__ __launch_bounds__(256) void dot_mfma(
    const unsigned short* __restrict__ Ehi, const unsigned short* __restrict__ Elo,
    float* __restrict__ dot)
{
  __shared__ __align__(16) unsigned short lb[2][16384]; // [hi/lo][c4][ot8][lane64][8]
  int t = threadIdx.x, wave = t>>6, lane = t&63;
  int arow0 = blockIdx.y*128, brow0 = blockIdx.x*128;
  {
    const unsigned short* srcp = (t<128) ? Ehi : Elo;
    unsigned short* dstb = lb[(t<128)?0:1];
    int o = t & 127;
    const unsigned short* rp = srcp + (size_t)(brow0+o)*128;
#pragma unroll
    for (int g=0; g<16; g++){
      short8v v = *reinterpret_cast<const short8v*>(rp + g*8);
      int c = g>>2, grp = g&3;
      int lidx = c*4096 + (o>>4)*512 + ((grp<<4)|(o&15))*8;
      *reinterpret_cast<short8v*>(&dstb[lidx]) = v;
    }
  }
  __syncthreads();

  floatx4 acc[2][8];
#pragma unroll
  for (int rt=0;rt<2;rt++)
#pragma unroll
    for (int ot=0;ot<8;ot++) acc[rt][ot] = (floatx4){0.f,0.f,0.f,0.f};

  int ar0 = arow0 + wave*32 + (lane&15);
  int ar1 = ar0 + 16;
  int koff = (lane>>4)*8;
#pragma unroll
  for (int c=0;c<4;c++){
    short8v ah0 = *reinterpret_cast<const short8v*>(Ehi + (size_t)ar0*128 + c*32 + koff);
    short8v ah1 = *reinterpret_cast<const short8v*>(Ehi + (size_t)ar1*128 + c*32 + koff);
    short8v al0 = *reinterpret_cast<const short8v*>(Elo + (size_t)ar0*128 + c*32 + koff);
    short8v al1 = *reinterpret_cast<const short8v*>(Elo + (size_t)ar1*128 + c*32 + koff);
#pragma unroll
    for (int ot=0;ot<8;ot++){
      short8v bh = *reinterpret_cast<const short8v*>(&lb[0][c*4096 + ot*512 + lane*8]);
      short8v bl = *reinterpret_cast<const short8v*>(&lb[1][c*4096 + ot*512 + lane*8]);
      acc[0][ot] = __builtin_amdgcn_mfma_f32_16x16x32_bf16(ah0, bh, acc[0][ot], 0,0,0);
      acc[0][ot] = __builtin_amdgcn_mfma_f32_16x16x32_bf16(ah0, bl, acc[0][ot], 0,0,0);
      acc[0][ot] = __builtin_amdgcn_mfma_f32_16x16x32_bf16(al0, bh, acc[0][ot], 0,0,0);
      acc[1][ot] = __builtin_amdgcn_mfma_f32_16x16x32_bf16(ah1, bh, acc[1][ot], 0,0,0);
      acc[1][ot] = __builtin_amdgcn_mfma_f32_16x16x32_bf16(ah1, bl, acc[1][ot], 0,0,0);
      acc[1][ot] = __builtin_amdgcn_mfma_f32_16x16x32_bf16(al1, bh, acc[1][ot], 0,0,0);
    }
  }
#pragma unroll
  for (int rt=0;rt<2;rt++){
    int rb = arow0 + wave*32 + rt*16 + (lane>>4)*4;
#pragma unroll
    for (int r=0;r<4;r++)
#pragma unroll
      for (int ot=0;ot<8;ot++)
        dot[(size_t)(rb+r)*4096 + brow0 + ot*16 + (lane&15)] = acc[rt][ot][r];
  }
}

extern "C" void kernel_launch(void* const* d_in, const int* in_sizes, int n_in,
                              void* d_out, int out_size, void* d_ws, size_t ws_size,
                              hipStream_t stream) {
  (void)in_sizes; (void)n_in; (void)out_size; (void)ws_size;
  const float* masks   = (const float*)d_in[0];
  const int*   n_ids   = (const int*)d_in[1];
  const int*   e0_src  = (const int*)d_in[2];
  const int*   e1_src  = (const int*)d_in[4];
  const float* pre_W   = (const float*)d_in[6];
  const float* pre_b   = (const float*)d_in[7];
  const float* gat_W   = (const float*)d_in[8];
  const float* gat_att = (const float*)d_in[9];
  const float* gat_b   = (const float*)d_in[10];
  const float* sp      = (const float*)d_in[11];
  const float* emb_W   = (const float*)d_in[12];
  const float* emb_b   = (const float*)d_in[13];

  float* out = (float*)d_out;
  float* dot = out;                         // [4096*4096]
  float* emb = out + (size_t)NB*NB;         // [4096*128]
  float* scales_out = emb + (size_t)NB*128; // [3]

  float* base = (float*)d_ws;
  unsigned short* WThi = (unsigned short*)base;              // IN_SZ*256 bf16
  unsigned short* WTlo = WThi + (size_t)IN_SZ*HD;            // IN_SZ*256 bf16
  float* xl   = base + (size_t)IN_SZ*HD;    // (hi+lo occupy IN_SZ*HD floats)
  float* g0   = xl + (size_t)N0*HD;
  float* xmod = g0 + (size_t)N1*HD;
  float* alph = xmod + (size_t)NB*HD;
  float* coef = alph + (size_t)N0*4;
  float* wT   = coef + NB*3;
  float* fend = wT + 32768;
  unsigned short* g0hi = (unsigned short*)fend;              // N1*256
  unsigned short* g0lo = g0hi + (size_t)N1*HD;
  unsigned short* gWhi = g0lo + (size_t)N1*HD;               // 3*256*256
  unsigned short* gWlo = gWhi + (size_t)NM*HD*HD;
  unsigned short* ehi  = gWlo + (size_t)NM*HD*HD;            // 4096*128
  unsigned short* elo  = ehi + (size_t)NB*128;

  interp_coef_k<<<64, 64, 0, stream>>>(masks, sp, coef, scales_out);
  transp_embW<<<128, 256, 0, stream>>>(emb_W, wT);
  split_k<<<(NM*HD*HD+255)/256, 256, 0, stream>>>(gat_W, gWhi, gWlo, NM*HD*HD);

  for (int i = 0; i < NM; i++) {
    transp_split_k<<<dim3((IN_SZ+31)/32, 8), 256, 0, stream>>>(
        pre_W + (size_t)i*HD*IN_SZ, pre_b + i*HD, WThi, WTlo);
    gemm_mfma<true><<<N0/64, 256, 0, stream>>>(
        WThi, WTlo, n_ids + (size_t)i*N0,
        gWhi + (size_t)i*HD*HD, gWlo + (size_t)i*HD*HD,
        xl, gat_att + i*HD, alph);
    gat_msg0<<<N1, 256, 0, stream>>>(xl, alph, e0_src + (size_t)i*E0, gat_b + i*HD,
                                     g0, g0hi, g0lo);
    gemm_mfma<false><<<N1/64, 256, 0, stream>>>(
        g0hi, g0lo, nullptr,
        gWhi + (size_t)i*HD*HD, gWlo + (size_t)i*HD*HD,
        xl, gat_att + i*HD, alph);
    gat_msg1<<<NB, 256, 0, stream>>>(xl, alph, e1_src + (size_t)i*E1, gat_b + i*HD,
                                     g0, coef, i, xmod);
  }
  emb_gemm<<<NB/32, 256, 0, stream>>>(xmod, wT, emb_b, emb, ehi, elo);
  dot_mfma<<<dim3(32,32), 256, 0, stream>>>(ehi, elo, dot);
}

// Round 4
// 404.433 us; speedup vs baseline: 3.3315x; 1.2953x over previous
//
#include <hip/hip_runtime.h>
#include <hip/hip_bf16.h>
#include <cstdint>

#define IN_SZ 50000
#define NM 3
#define N0 40960
#define N1 16384
#define NB 4096
#define HD 256
#define DEG 16
#define E0 (N1*DEG)
#define E1 (NB*DEG)

using short8v = __attribute__((ext_vector_type(8))) short;
using floatx4 = __attribute__((ext_vector_type(4))) float;
typedef unsigned short ushort_t;

__device__ __forceinline__ ushort_t f2bf(float f){
  uint32_t u = __float_as_uint(f);
  uint32_t r = u + 0x7FFFu + ((u>>16)&1u);
  return (ushort_t)(r>>16);
}
__device__ __forceinline__ float bf2f(ushort_t h){
  return __uint_as_float(((uint32_t)h)<<16);
}

// ---------------- threefry2x32 (JAX-exact) ----------------
__device__ __forceinline__ uint32_t rotl32(uint32_t x, uint32_t d){ return (x<<d)|(x>>(32u-d)); }

__device__ void tf2x32(uint32_t k0, uint32_t k1, uint32_t c0, uint32_t c1,
                       uint32_t& y0, uint32_t& y1)
{
  uint32_t ks2 = k0 ^ k1 ^ 0x1BD11BDAu;
  uint32_t x0 = c0 + k0, x1 = c1 + k1;
#define R4(a,b,c,d) \
  x0+=x1; x1=rotl32(x1,a); x1^=x0; \
  x0+=x1; x1=rotl32(x1,b); x1^=x0; \
  x0+=x1; x1=rotl32(x1,c); x1^=x0; \
  x0+=x1; x1=rotl32(x1,d); x1^=x0;
  R4(13,15,26,6)  x0+=k1;  x1+=ks2+1u;
  R4(17,29,16,24) x0+=ks2; x1+=k0+2u;
  R4(13,15,26,6)  x0+=k0;  x1+=k1+3u;
  R4(17,29,16,24) x0+=k1;  x1+=ks2+4u;
  R4(13,15,26,6)  x0+=ks2; x1+=k0+5u;
#undef R4
  y0=x0; y1=x1;
}

__global__ void interp_coef_k(const float* __restrict__ masks, const float* __restrict__ sp,
                              float* __restrict__ coef, float* __restrict__ scales_out)
{
  int b = blockIdx.x*256 + threadIdx.x;
  if (b >= NB) return;
  float s0=sp[0], s1=sp[1], s2=sp[2];
  float mx = fmaxf(s0,fmaxf(s1,s2));
  float e0=expf(s0-mx), e1=expf(s1-mx), e2=expf(s2-mx);
  float inv = 1.f/(e0+e1+e2);
  float sc[3] = {e0*inv, e1*inv, e2*inv};
  if (b == 0){ scales_out[0]=sc[0]; scales_out[1]=sc[1]; scales_out[2]=sc[2]; }

  uint32_t bits[3];
  uint32_t K0,K1, t0,t1;
  tf2x32(0u,42u,0u,1u,K0,K1);
  for (int i=0;i<3;i++){
    uint32_t idx = (uint32_t)(b*3+i);
    tf2x32(K0,K1,0u,idx,t0,t1);
    bits[i] = (t0 ^ t1) & 1u;
  }
  float mk[3] = {masks[b*3+0], masks[b*3+1], masks[b*3+2]};
  float msum = mk[0]+mk[1]+mk[2];
  float rs = (float)(bits[0]+bits[1]+bits[2]);
  float add = powf(1.f/(1.f+rs), 20.f) + powf(1.f/msum, 20.f);
  float lg[3]; float lmax = -1e30f;
  for (int i=0;i<3;i++){
    float rm = floorf((float)bits[i] + add);
    rm = rm/(rm+1e-10f);
    float mm = mk[i]*rm;
    lg[i] = mm + (1.f-mm)*(-1e10f);
    lmax = fmaxf(lmax, lg[i]);
  }
  float es[3], ssum=0.f;
  for (int i=0;i<3;i++){ es[i]=expf(lg[i]-lmax); ssum+=es[i]; }
  for (int i=0;i<3;i++) coef[b*3+i] = sc[i]*es[i]/ssum;
}

// ---- batched transpose+split pre_W [256,50000] -> WThi/WTlo [50000,256] bf16, bias baked
__global__ __launch_bounds__(256) void transp_split_k(const float* __restrict__ Wb,
                                                      const float* __restrict__ bb,
                                                      ushort_t* __restrict__ WThi_b,
                                                      ushort_t* __restrict__ WTlo_b)
{
  int i = blockIdx.z;
  const float* W = Wb + (size_t)i*HD*IN_SZ;
  const float* bvec = bb + i*HD;
  ushort_t* WThi = WThi_b + (size_t)i*IN_SZ*HD;
  ushort_t* WTlo = WTlo_b + (size_t)i*IN_SZ*HD;
  __shared__ float tile[32][33];
  int c0 = blockIdx.x*32, k0 = blockIdx.y*32;
  int tx = threadIdx.x & 31, tg = threadIdx.x >> 5;
#pragma unroll
  for (int j=0;j<4;j++){
    int k = k0 + tg*4 + j;
    int c = c0 + tx;
    tile[tg*4+j][tx] = (c < IN_SZ) ? W[(size_t)k*IN_SZ + c] : 0.f;
  }
  __syncthreads();
#pragma unroll
  for (int j=0;j<4;j++){
    int c = c0 + tg*4 + j;
    int k = k0 + tx;
    if (c < IN_SZ){
      float v = tile[tx][tg*4+j] + bvec[k];
      ushort_t h = f2bf(v);
      WThi[(size_t)c*HD + k] = h;
      WTlo[(size_t)c*HD + k] = f2bf(v - bf2f(h));
    }
  }
}

// ---- elementwise hi/lo split (gat_W, all modalities at once) ----
__global__ void split_k(const float* __restrict__ src, ushort_t* __restrict__ hi,
                        ushort_t* __restrict__ lo, int n)
{
  int g = blockIdx.x*256 + threadIdx.x;
  if (g >= n) return;
  float v = src[g];
  ushort_t h = f2bf(v);
  hi[g] = h;
  lo[g] = f2bf(v - bf2f(h));
}

// ---- MFMA GEMM batched over modality (blockIdx.y); 3-term bf16 split ----
// C(bf16 hi) [rows,256]; fused alpha epilogue.
template<bool HAS_IDS>
__global__ __launch_bounds__(256) void gemm_mfma(
    const ushort_t* __restrict__ Ahi_b, const ushort_t* __restrict__ Alo_b, size_t a_stride,
    const int* __restrict__ ids_b, int ids_n,
    const ushort_t* __restrict__ Whi_b, const ushort_t* __restrict__ Wlo_b,
    ushort_t* __restrict__ Chi_b, size_t c_stride,
    const float* __restrict__ att_b, float* __restrict__ alpha_b, size_t al_stride)
{
  int i = blockIdx.y;
  const ushort_t* Ahi = Ahi_b + (size_t)i*a_stride;
  const ushort_t* Alo = Alo_b + (size_t)i*a_stride;
  const ushort_t* Whi = Whi_b + (size_t)i*HD*HD;
  const ushort_t* Wlo = Wlo_b + (size_t)i*HD*HD;
  ushort_t* Chi = Chi_b + (size_t)i*c_stride;
  const float* att = att_b + (size_t)i*HD;
  float* alpha = alpha_b + (size_t)i*al_stride;

  __shared__ __align__(16) ushort_t lbh[8192];  // [ot16][lane64][8] fragment-ordered
  __shared__ __align__(16) ushort_t lbl[8192];
  __shared__ int sid[64];
  int t = threadIdx.x;
  int wave = t>>6, lane = t&63;
  int block_row = blockIdx.x*64;
  if (HAS_IDS && t < 64) sid[t] = ids_b[(size_t)i*ids_n + block_row + t];
  __syncthreads();

  int arow;
  if (HAS_IDS) arow = sid[wave*16 + (lane&15)];
  else         arow = block_row + wave*16 + (lane&15);
  const ushort_t* aphi = Ahi + (size_t)arow*HD + ((lane>>4)*8);
  const ushort_t* aplo = Alo + (size_t)arow*HD + ((lane>>4)*8);

  floatx4 acc[16];
#pragma unroll
  for (int k=0;k<16;k++) acc[k] = (floatx4){0.f,0.f,0.f,0.f};

  const int o = t;
  for (int k0=0; k0<256; k0+=32){
    short8v wh[4], wl[4];
#pragma unroll
    for (int g=0; g<4; g++){
      wh[g] = *reinterpret_cast<const short8v*>(Whi + (size_t)o*HD + k0 + g*8);
      wl[g] = *reinterpret_cast<const short8v*>(Wlo + (size_t)o*HD + k0 + g*8);
    }
    short8v ah = *reinterpret_cast<const short8v*>(aphi + k0);
    short8v al = *reinterpret_cast<const short8v*>(aplo + k0);
    __syncthreads();
#pragma unroll
    for (int g=0; g<4; g++){
      int idx = (o>>4)*512 + ((g<<4)|(o&15))*8;
      *reinterpret_cast<short8v*>(&lbh[idx]) = wh[g];
      *reinterpret_cast<short8v*>(&lbl[idx]) = wl[g];
    }
    __syncthreads();
#pragma unroll
    for (int ot=0; ot<16; ot++){
      short8v bh = *reinterpret_cast<const short8v*>(&lbh[ot*512 + lane*8]);
      short8v bl = *reinterpret_cast<const short8v*>(&lbl[ot*512 + lane*8]);
      acc[ot] = __builtin_amdgcn_mfma_f32_16x16x32_bf16(ah, bh, acc[ot], 0, 0, 0);
      acc[ot] = __builtin_amdgcn_mfma_f32_16x16x32_bf16(ah, bl, acc[ot], 0, 0, 0);
      acc[ot] = __builtin_amdgcn_mfma_f32_16x16x32_bf16(al, bh, acc[ot], 0, 0, 0);
    }
  }

  float attv[16];
#pragma unroll
  for (int ot=0; ot<16; ot++) attv[ot] = att[ot*16 + (lane&15)];
  int rbase = block_row + wave*16 + (lane>>4)*4;
#pragma unroll
  for (int r=0; r<4; r++){
    size_t row = (size_t)(rbase + r);
#pragma unroll
    for (int ot=0; ot<16; ot++) Chi[row*HD + ot*16 + (lane&15)] = f2bf(acc[ot][r]);
#pragma unroll
    for (int h=0; h<4; h++){
      float p = acc[4*h+0][r]*attv[4*h+0] + acc[4*h+1][r]*attv[4*h+1]
              + acc[4*h+2][r]*attv[4*h+2] + acc[4*h+3][r]*attv[4*h+3];
      p += __shfl_xor(p, 1, 64);
      p += __shfl_xor(p, 2, 64);
      p += __shfl_xor(p, 4, 64);
      p += __shfl_xor(p, 8, 64);
      if ((lane&15) == 0) alpha[row*4 + h] = p;
    }
  }
}

// ---- layer-0 GAT message (batched): reads bf16 xl, writes packed g0 hi/lo ----
__global__ __launch_bounds__(128) void gat_msg0(
    const ushort_t* __restrict__ xlhi_b, const float* __restrict__ alpha_b,
    const int* __restrict__ esrc_b, const float* __restrict__ bias_b,
    uint32_t* __restrict__ g0hi_u, uint32_t* __restrict__ g0lo_u)
{
  int i = blockIdx.y;
  int d = blockIdx.x;
  const ushort_t* xl = xlhi_b + (size_t)i*N0*HD;
  const float* alpha = alpha_b + (size_t)i*N0*4;
  const float* bias = bias_b + i*HD;
  int t = threadIdx.x;
  __shared__ int src[16];
  __shared__ float aw[16][4];
  if (t < 16) src[t] = esrc_b[(size_t)i*E0 + d*16 + t];
  __syncthreads();
  if (t < 64) {
    int e = t & 15, h = t >> 4;
    float l = alpha[(size_t)src[e]*4 + h];
    l = l > 0.f ? l : 0.2f*l;
    float m = l;
#pragma unroll
    for (int off=1; off<16; off<<=1) m = fmaxf(m, __shfl_xor(m, off, 64));
    float ex = expf(l - m);
    float s = ex;
#pragma unroll
    for (int off=1; off<16; off<<=1) s += __shfl_xor(s, off, 64);
    aw[e][h] = ex / (s + 1e-16f);
  }
  __syncthreads();
  int h = t >> 5;                      // head of column 2t
  float a0=0.f, a1=0.f;
#pragma unroll
  for (int e=0;e<16;e++){
    uint32_t u = *reinterpret_cast<const uint32_t*>(xl + (size_t)src[e]*HD + 2*t);
    float w = aw[e][h];
    a0 = fmaf(w, bf2f((ushort_t)(u & 0xffffu)), a0);
    a1 = fmaf(w, bf2f((ushort_t)(u >> 16)), a1);
  }
  float v0 = a0 + bias[2*t], v1 = a1 + bias[2*t+1];
  ushort_t h0 = f2bf(v0), h1 = f2bf(v1);
  ushort_t l0 = f2bf(v0 - bf2f(h0)), l1 = f2bf(v1 - bf2f(h1));
  size_t gi = ((size_t)i*N1 + d)*128 + t;
  g0hi_u[gi] = (uint32_t)h0 | ((uint32_t)h1<<16);
  g0lo_u[gi] = (uint32_t)l0 | ((uint32_t)l1<<16);
}

// ---- layer-1 GAT message: loops modalities, fused gate+accumulate -> xmod fp32 ----
__global__ __launch_bounds__(128) void gat_msg1(
    const ushort_t* __restrict__ xl1hi, const float* __restrict__ alpha1,
    const int* __restrict__ e1src, const float* __restrict__ gat_b,
    const uint32_t* __restrict__ g0hi_u, const uint32_t* __restrict__ g0lo_u,
    const float* __restrict__ coef, float* __restrict__ xmod)
{
  int d = blockIdx.x;
  int t = threadIdx.x;
  __shared__ int src[16];
  __shared__ float aw[16][4];
  float o0 = 0.f, o1 = 0.f;
  for (int i=0;i<NM;i++){
    if (t < 16) src[t] = e1src[(size_t)i*E1 + d*16 + t];
    __syncthreads();
    if (t < 64) {
      int e = t & 15, h = t >> 4;
      float l = alpha1[((size_t)i*N1 + src[e])*4 + h];
      l = l > 0.f ? l : 0.2f*l;
      float m = l;
#pragma unroll
      for (int off=1; off<16; off<<=1) m = fmaxf(m, __shfl_xor(m, off, 64));
      float ex = expf(l - m);
      float s = ex;
#pragma unroll
      for (int off=1; off<16; off<<=1) s += __shfl_xor(s, off, 64);
      aw[e][h] = ex / (s + 1e-16f);
    }
    __syncthreads();
    const ushort_t* xl = xl1hi + (size_t)i*N1*HD;
    int h = t >> 5;
    float a0=0.f, a1=0.f;
#pragma unroll
    for (int e=0;e<16;e++){
      uint32_t u = *reinterpret_cast<const uint32_t*>(xl + (size_t)src[e]*HD + 2*t);
      float w = aw[e][h];
      a0 = fmaf(w, bf2f((ushort_t)(u & 0xffffu)), a0);
      a1 = fmaf(w, bf2f((ushort_t)(u >> 16)), a1);
    }
    size_t gi = ((size_t)i*N1 + d)*128 + t;
    uint32_t gh = g0hi_u[gi], gl = g0lo_u[gi];
    float g00 = bf2f((ushort_t)(gh & 0xffffu)) + bf2f((ushort_t)(gl & 0xffffu));
    float g01 = bf2f((ushort_t)(gh >> 16))    + bf2f((ushort_t)(gl >> 16));
    const float* bias = gat_b + i*HD;
    float cv = coef[d*3 + i];
    o0 += cv*(2.f*g00 + 2.f*(a0 + bias[2*t]));
    o1 += cv*(2.f*g01 + 2.f*(a1 + bias[2*t+1]));
    __syncthreads();
  }
  *reinterpret_cast<float2*>(&xmod[(size_t)d*HD + 2*t]) = make_float2(o0, o1);
}

// ---- emb_W transpose [128,256]->[256,128] ----
__global__ void transp_embW(const float* __restrict__ w, float* __restrict__ wt)
{
  int g = blockIdx.x*256 + threadIdx.x;
  int j = g >> 8, k = g & 255;
  wt[k*128 + j] = w[g];
}

// ---- emb = xmod @ embW^T + b; writes fp32 + hi/lo bf16 ----
__global__ __launch_bounds__(256) void emb_gemm(
  const float* __restrict__ xmod, const float* __restrict__ wT,
  const float* __restrict__ eb, float* __restrict__ emb,
  ushort_t* __restrict__ ehi, ushort_t* __restrict__ elo)
{
  __shared__ float xs[32][260];
  int t = threadIdx.x;
  int brow = blockIdx.x * 32;
#pragma unroll
  for (int j=0;j<8;j++){
    int linear = j*256+t;
    int row = linear >> 6;
    int kq = linear & 63;
    float4 f = *reinterpret_cast<const float4*>(&xmod[(size_t)(brow+row)*256 + kq*4]);
    xs[row][kq*4+0]=f.x; xs[row][kq*4+1]=f.y; xs[row][kq*4+2]=f.z; xs[row][kq*4+3]=f.w;
  }
  __syncthreads();
  int tj = t & 127, th = t >> 7;
  float acc[16];
#pragma unroll
  for(int r=0;r<16;r++) acc[r]=0.f;
  for (int k=0;k<256;k++){
    float w = wT[k*128 + tj];
#pragma unroll
    for (int r=0;r<16;r++) acc[r] = fmaf(xs[th*16+r][k], w, acc[r]);
  }
  float bias = eb[tj];
#pragma unroll
  for (int r=0;r<16;r++){
    size_t idx = (size_t)(brow+th*16+r)*128 + tj;
    float v = acc[r] + bias;
    emb[idx] = v;
    ushort_t hb = f2bf(v);
    ehi[idx] = hb;
    elo[idx] = f2bf(v - bf2f(hb));
  }
}

// ---- dot = emb @ emb^T via MFMA, 3-term split ----
__global__ __launch_bounds__(256) void dot_mfma(
    const ushort_t* __restrict__ Ehi, const ushort_t* __restrict__ Elo,
    float* __restrict__ dot)
{
  __shared__ __align__(16) ushort_t lb[2][16384];
  int t = threadIdx.x, wave = t>>6, lane = t&63;
  int arow0 = blockIdx.y*128, brow0 = blockIdx.x*128;
  {
    const ushort_t* srcp = (t<128) ? Ehi : Elo;
    ushort_t* dstb = lb[(t<128)?0:1];
    int o = t & 127;
    const ushort_t* rp = srcp + (size_t)(brow0+o)*128;
#pragma unroll
    for (int g=0; g<16; g++){
      short8v v = *reinterpret_cast<const short8v*>(rp + g*8);
      int c = g>>2, grp = g&3;
      int lidx = c*4096 + (o>>4)*512 + ((grp<<4)|(o&15))*8;
      *reinterpret_cast<short8v*>(&dstb[lidx]) = v;
    }
  }
  __syncthreads();

  floatx4 acc[2][8];
#pragma unroll
  for (int rt=0;rt<2;rt++)
#pragma unroll
    for (int ot=0;ot<8;ot++) acc[rt][ot] = (floatx4){0.f,0.f,0.f,0.f};

  int ar0 = arow0 + wave*32 + (lane&15);
  int ar1 = ar0 + 16;
  int koff = (lane>>4)*8;
#pragma unroll
  for (int c=0;c<4;c++){
    short8v ah0 = *reinterpret_cast<const short8v*>(Ehi + (size_t)ar0*128 + c*32 + koff);
    short8v ah1 = *reinterpret_cast<const short8v*>(Ehi + (size_t)ar1*128 + c*32 + koff);
    short8v al0 = *reinterpret_cast<const short8v*>(Elo + (size_t)ar0*128 + c*32 + koff);
    short8v al1 = *reinterpret_cast<const short8v*>(Elo + (size_t)ar1*128 + c*32 + koff);
#pragma unroll
    for (int ot=0;ot<8;ot++){
      short8v bh = *reinterpret_cast<const short8v*>(&lb[0][c*4096 + ot*512 + lane*8]);
      short8v bl = *reinterpret_cast<const short8v*>(&lb[1][c*4096 + ot*512 + lane*8]);
      acc[0][ot] = __builtin_amdgcn_mfma_f32_16x16x32_bf16(ah0, bh, acc[0][ot], 0,0,0);
      acc[0][ot] = __builtin_amdgcn_mfma_f32_16x16x32_bf16(ah0, bl, acc[0][ot], 0,0,0);
      acc[0][ot] = __builtin_amdgcn_mfma_f32_16x16x32_bf16(al0, bh, acc[0][ot], 0,0,0);
      acc[1][ot] = __builtin_amdgcn_mfma_f32_16x16x32_bf16(ah1, bh, acc[1][ot], 0,0,0);
      acc[1][ot] = __builtin_amdgcn_mfma_f32_16x16x32_bf16(ah1, bl, acc[1][ot], 0,0,0);
      acc[1][ot] = __builtin_amdgcn_mfma_f32_16x16x32_bf16(al1, bh, acc[1][ot], 0,0,0);
    }
  }
#pragma unroll
  for (int rt=0;rt<2;rt++){
    int rb = arow0 + wave*32 + rt*16 + (lane>>4)*4;
#pragma unroll
    for (int r=0;r<4;r++)
#pragma unroll
      for (int ot=0;ot<8;ot++)
        dot[(size_t)(rb+r)*4096 + brow0 + ot*16 + (lane&15)] = acc[rt][ot][r];
  }
}

extern "C" void kernel_launch(void* const* d_in, const int* in_sizes, int n_in,
                              void* d_out, int out_size, void* d_ws, size_t ws_size,
                              hipStream_t stream) {
  (void)in_sizes; (void)n_in; (void)out_size; (void)ws_size;
  const float* masks   = (const float*)d_in[0];
  const int*   n_ids   = (const int*)d_in[1];
  const int*   e0_src  = (const int*)d_in[2];
  const int*   e1_src  = (const int*)d_in[4];
  const float* pre_W   = (const float*)d_in[6];
  const float* pre_b   = (const float*)d_in[7];
  const float* gat_W   = (const float*)d_in[8];
  const float* gat_att = (const float*)d_in[9];
  const float* gat_b   = (const float*)d_in[10];
  const float* sp      = (const float*)d_in[11];
  const float* emb_W   = (const float*)d_in[12];
  const float* emb_b   = (const float*)d_in[13];

  float* out = (float*)d_out;
  float* dot = out;                         // [4096*4096]
  float* emb = out + (size_t)NB*NB;         // [4096*128]
  float* scales_out = emb + (size_t)NB*128; // [3]

  char* p = (char*)d_ws;
  auto alloc = [&](size_t bytes)->char*{ char* r = p; p += (bytes + 255) & ~(size_t)255; return r; };
  ushort_t* WThi  = (ushort_t*)alloc((size_t)NM*IN_SZ*HD*2);
  ushort_t* WTlo  = (ushort_t*)alloc((size_t)NM*IN_SZ*HD*2);
  ushort_t* xlhi  = (ushort_t*)alloc((size_t)NM*N0*HD*2);
  uint32_t* g0hi  = (uint32_t*)alloc((size_t)NM*N1*HD*2);
  uint32_t* g0lo  = (uint32_t*)alloc((size_t)NM*N1*HD*2);
  ushort_t* xl1hi = (ushort_t*)alloc((size_t)NM*N1*HD*2);
  float*    alph0 = (float*)alloc((size_t)NM*N0*4*4);
  float*    alph1 = (float*)alloc((size_t)NM*N1*4*4);
  float*    xmod  = (float*)alloc((size_t)NB*HD*4);
  float*    coef  = (float*)alloc((size_t)NB*3*4);
  float*    wT    = (float*)alloc((size_t)HD*128*4);
  ushort_t* gWhi  = (ushort_t*)alloc((size_t)NM*HD*HD*2);
  ushort_t* gWlo  = (ushort_t*)alloc((size_t)NM*HD*HD*2);
  ushort_t* ehi   = (ushort_t*)alloc((size_t)NB*128*2);
  ushort_t* elo   = (ushort_t*)alloc((size_t)NB*128*2);

  interp_coef_k<<<16, 256, 0, stream>>>(masks, sp, coef, scales_out);
  transp_embW<<<128, 256, 0, stream>>>(emb_W, wT);
  split_k<<<(NM*HD*HD+255)/256, 256, 0, stream>>>(gat_W, gWhi, gWlo, NM*HD*HD);
  transp_split_k<<<dim3((IN_SZ+31)/32, 8, NM), 256, 0, stream>>>(pre_W, pre_b, WThi, WTlo);

  gemm_mfma<true><<<dim3(N0/64, NM), 256, 0, stream>>>(
      WThi, WTlo, (size_t)IN_SZ*HD, n_ids, N0,
      gWhi, gWlo, xlhi, (size_t)N0*HD, gat_att, alph0, (size_t)N0*4);
  gat_msg0<<<dim3(N1, NM), 128, 0, stream>>>(xlhi, alph0, e0_src, gat_b, g0hi, g0lo);
  gemm_mfma<false><<<dim3(N1/64, NM), 256, 0, stream>>>(
      (const ushort_t*)g0hi, (const ushort_t*)g0lo, (size_t)N1*HD, nullptr, 0,
      gWhi, gWlo, xl1hi, (size_t)N1*HD, gat_att, alph1, (size_t)N1*4);
  gat_msg1<<<NB, 128, 0, stream>>>(xl1hi, alph1, e1_src, gat_b, g0hi, g0lo, coef, xmod);
  emb_gemm<<<NB/32, 256, 0, stream>>>(xmod, wT, emb_b, emb, ehi, elo);
  dot_mfma<<<dim3(32,32), 256, 0, stream>>>(ehi, elo, dot);
}

// Round 5
// 291.784 us; speedup vs baseline: 4.6177x; 1.3861x over previous
//
#include <hip/hip_runtime.h>
#include <hip/hip_bf16.h>
#include <cstdint>

#define IN_SZ 50000
#define NM 3
#define N0 40960
#define N1 16384
#define NB 4096
#define HD 256
#define DEG 16
#define E0 (N1*DEG)
#define E1 (NB*DEG)

using short8v = __attribute__((ext_vector_type(8))) short;
using floatx4 = __attribute__((ext_vector_type(4))) float;
typedef unsigned short ushort_t;

__device__ __forceinline__ ushort_t f2bf(float f){
  uint32_t u = __float_as_uint(f);
  uint32_t r = u + 0x7FFFu + ((u>>16)&1u);
  return (ushort_t)(r>>16);
}
__device__ __forceinline__ float bf2f(ushort_t h){
  return __uint_as_float(((uint32_t)h)<<16);
}
__device__ __forceinline__ void gload_lds16(const ushort_t* g, ushort_t* l){
  __builtin_amdgcn_global_load_lds(
      (const __attribute__((address_space(1))) void*)g,
      (__attribute__((address_space(3))) void*)l, 16, 0, 0);
}

// ---------------- threefry2x32 (JAX-exact) ----------------
__device__ __forceinline__ uint32_t rotl32(uint32_t x, uint32_t d){ return (x<<d)|(x>>(32u-d)); }

__device__ void tf2x32(uint32_t k0, uint32_t k1, uint32_t c0, uint32_t c1,
                       uint32_t& y0, uint32_t& y1)
{
  uint32_t ks2 = k0 ^ k1 ^ 0x1BD11BDAu;
  uint32_t x0 = c0 + k0, x1 = c1 + k1;
#define R4(a,b,c,d) \
  x0+=x1; x1=rotl32(x1,a); x1^=x0; \
  x0+=x1; x1=rotl32(x1,b); x1^=x0; \
  x0+=x1; x1=rotl32(x1,c); x1^=x0; \
  x0+=x1; x1=rotl32(x1,d); x1^=x0;
  R4(13,15,26,6)  x0+=k1;  x1+=ks2+1u;
  R4(17,29,16,24) x0+=ks2; x1+=k0+2u;
  R4(13,15,26,6)  x0+=k0;  x1+=k1+3u;
  R4(17,29,16,24) x0+=k1;  x1+=ks2+4u;
  R4(13,15,26,6)  x0+=ks2; x1+=k0+5u;
#undef R4
  y0=x0; y1=x1;
}

__global__ void interp_coef_k(const float* __restrict__ masks, const float* __restrict__ sp,
                              float* __restrict__ coef, float* __restrict__ scales_out)
{
  int b = blockIdx.x*256 + threadIdx.x;
  if (b >= NB) return;
  float s0=sp[0], s1=sp[1], s2=sp[2];
  float mx = fmaxf(s0,fmaxf(s1,s2));
  float e0=expf(s0-mx), e1=expf(s1-mx), e2=expf(s2-mx);
  float inv = 1.f/(e0+e1+e2);
  float sc[3] = {e0*inv, e1*inv, e2*inv};
  if (b == 0){ scales_out[0]=sc[0]; scales_out[1]=sc[1]; scales_out[2]=sc[2]; }

  uint32_t bits[3];
  uint32_t K0,K1, t0,t1;
  tf2x32(0u,42u,0u,1u,K0,K1);
  for (int i=0;i<3;i++){
    uint32_t idx = (uint32_t)(b*3+i);
    tf2x32(K0,K1,0u,idx,t0,t1);
    bits[i] = (t0 ^ t1) & 1u;
  }
  float mk[3] = {masks[b*3+0], masks[b*3+1], masks[b*3+2]};
  float msum = mk[0]+mk[1]+mk[2];
  float rs = (float)(bits[0]+bits[1]+bits[2]);
  float add = powf(1.f/(1.f+rs), 20.f) + powf(1.f/msum, 20.f);
  float lg[3]; float lmax = -1e30f;
  for (int i=0;i<3;i++){
    float rm = floorf((float)bits[i] + add);
    rm = rm/(rm+1e-10f);
    float mm = mk[i]*rm;
    lg[i] = mm + (1.f-mm)*(-1e10f);
    lmax = fmaxf(lmax, lg[i]);
  }
  float es[3], ssum=0.f;
  for (int i=0;i<3;i++){ es[i]=expf(lg[i]-lmax); ssum+=es[i]; }
  for (int i=0;i<3;i++) coef[b*3+i] = sc[i]*es[i]/ssum;
}

// ---- transpose pre_W [256,50000] -> WThi [50000,256] bf16 (no bias) ----
__global__ __launch_bounds__(256) void transp_k(const float* __restrict__ Wb,
                                                ushort_t* __restrict__ WT_b)
{
  int i = blockIdx.z;
  const float* W = Wb + (size_t)i*HD*IN_SZ;
  ushort_t* WT = WT_b + (size_t)i*IN_SZ*HD;
  __shared__ float tile[32][33];
  int c0 = blockIdx.x*32, k0 = blockIdx.y*32;
  int tx = threadIdx.x & 31, tg = threadIdx.x >> 5;
#pragma unroll
  for (int j=0;j<4;j++){
    int k = k0 + tg*4 + j, c = c0 + tx;
    tile[tg*4+j][tx] = (c < IN_SZ) ? W[(size_t)k*IN_SZ + c] : 0.f;
  }
  __syncthreads();
#pragma unroll
  for (int j=0;j<4;j++){
    int c = c0 + tg*4 + j, k = k0 + tx;
    if (c < IN_SZ) WT[(size_t)c*HD + k] = f2bf(tile[tx][tg*4+j]);
  }
}

// ---- elementwise hi/lo split (gat_W) ----
__global__ void split_k(const float* __restrict__ src, ushort_t* __restrict__ hi,
                        ushort_t* __restrict__ lo, int n)
{
  int g = blockIdx.x*256 + threadIdx.x;
  if (g >= n) return;
  float v = src[g];
  ushort_t h = f2bf(v);
  hi[g] = h;
  lo[g] = f2bf(v - bf2f(h));
}

// ---- bias2[i][o] = sum_k pre_b[i][k]*gat_W[i][o][k] (fp32, exact bias path) ----
__global__ void bias_gemv_k(const float* __restrict__ pre_b, const float* __restrict__ gat_W,
                            float* __restrict__ bias2)
{
  int i = blockIdx.x, o = threadIdx.x;
  const float* W = gat_W + (size_t)i*HD*HD + (size_t)o*HD;
  const float* b = pre_b + i*HD;
  float s = 0.f;
  for (int k=0;k<HD;k++) s = fmaf(b[k], W[k], s);
  bias2[i*HD + o] = s;
}

// ---- MFMA GEMM: 128x128 tile, global_load_lds staging, 2-term (Ahi*Whi + Ahi*Wlo) ----
// Fused fp32 bias add + leaky-relu'd alpha epilogue. C in bf16.
template<bool HAS_IDS, bool ADD_BIAS>
__global__ __launch_bounds__(256) void gemm2(
    const ushort_t* __restrict__ A_b, size_t a_stride,
    const int* __restrict__ ids_b, int ids_n,
    const ushort_t* __restrict__ Whi_b, const ushort_t* __restrict__ Wlo_b,
    const float* __restrict__ bias2_b,
    ushort_t* __restrict__ C_b, size_t c_stride,
    const float* __restrict__ att_b, float* __restrict__ alpha_b, size_t al_stride)
{
  int i = blockIdx.z;
  int bn0 = blockIdx.y * 128;
  int brow = blockIdx.x * 128;
  const ushort_t* A = A_b + (size_t)i*a_stride;
  const ushort_t* Whi = Whi_b + (size_t)i*HD*HD;
  const ushort_t* Wlo = Wlo_b + (size_t)i*HD*HD;
  ushort_t* C = C_b + (size_t)i*c_stride;
  const float* att = att_b + (size_t)i*HD;
  float* alpha = alpha_b + (size_t)i*al_stride;

  // 24 frags/chunk (8 A + 16 B hi/lo) x 1KB, double-buffered
  __shared__ __align__(16) ushort_t smem[2][24*512];
  __shared__ int sid[128];
  int t = threadIdx.x, wave = t>>6, lane = t&63;
  int l15 = lane&15, kq = lane>>4;

  if constexpr (HAS_IDS){
    if (t < 128) sid[t] = ids_b[(size_t)i*ids_n + brow + t];
    __syncthreads();
  }
  int row0, row1;
  if constexpr (HAS_IDS){ row0 = sid[wave*16 + l15]; row1 = sid[(wave+4)*16 + l15]; }
  else                  { row0 = brow + wave*16 + l15; row1 = brow + (wave+4)*16 + l15; }

  // per-wave staged fragments: f = wave + 4j, j=0..5 (j<2: A rt=f; j>=2: B idx=f-8)
  const ushort_t* gsrc[6];
  gsrc[0] = A + (size_t)row0*HD + kq*8;
  gsrc[1] = A + (size_t)row1*HD + kq*8;
#pragma unroll
  for (int j=2;j<6;j++){
    int idx = wave + 4*(j-2);
    int ct = idx>>1, h = idx&1;
    const ushort_t* W = h ? Wlo : Whi;
    gsrc[j] = W + (size_t)(bn0 + ct*16 + l15)*HD + kq*8;
  }

  floatx4 acc[4][4];
#pragma unroll
  for (int r=0;r<4;r++)
#pragma unroll
    for (int c=0;c<4;c++) acc[r][c] = (floatx4){0.f,0.f,0.f,0.f};

  int wm = wave>>1, wn = wave&1;

#pragma unroll
  for (int j=0;j<6;j++)
    gload_lds16(gsrc[j], &smem[0][(wave + 4*j)*512]);
  __syncthreads();

  for (int cc=0; cc<8; cc++){
    int buf = cc & 1;
    if (cc < 7){
      int k0 = (cc+1)*32;
#pragma unroll
      for (int j=0;j<6;j++)
        gload_lds16(gsrc[j] + k0, &smem[buf^1][(wave + 4*j)*512]);
    }
    short8v a[4];
#pragma unroll
    for (int r=0;r<4;r++)
      a[r] = *reinterpret_cast<const short8v*>(&smem[buf][(wm*4+r)*512 + lane*8]);
#pragma unroll
    for (int c=0;c<4;c++){
      int ct = wn*4+c;
      short8v bh = *reinterpret_cast<const short8v*>(&smem[buf][(8+ct*2)*512 + lane*8]);
      short8v bl = *reinterpret_cast<const short8v*>(&smem[buf][(9+ct*2)*512 + lane*8]);
#pragma unroll
      for (int r=0;r<4;r++){
        acc[r][c] = __builtin_amdgcn_mfma_f32_16x16x32_bf16(a[r], bh, acc[r][c], 0,0,0);
        acc[r][c] = __builtin_amdgcn_mfma_f32_16x16x32_bf16(a[r], bl, acc[r][c], 0,0,0);
      }
    }
    __syncthreads();
  }

  float attv[4], bias2v[4];
#pragma unroll
  for (int c=0;c<4;c++){
    int col = bn0 + (wn*4+c)*16 + l15;
    attv[c] = att[col];
    if constexpr (ADD_BIAS) bias2v[c] = bias2_b[i*HD + col];
  }
  int head = (bn0>>6) + wn;
#pragma unroll
  for (int r=0;r<4;r++){
    int rowb = brow + wm*64 + r*16 + kq*4;
    if constexpr (ADD_BIAS){
#pragma unroll
      for (int c=0;c<4;c++)
#pragma unroll
        for (int j=0;j<4;j++) acc[r][c][j] += bias2v[c];
    }
#pragma unroll
    for (int j=0;j<4;j++){
      size_t rw = (size_t)(rowb + j)*HD;
#pragma unroll
      for (int c=0;c<4;c++)
        C[rw + bn0 + (wn*4+c)*16 + l15] = f2bf(acc[r][c][j]);
    }
#pragma unroll
    for (int j=0;j<4;j++){
      float p = acc[r][0][j]*attv[0] + acc[r][1][j]*attv[1]
              + acc[r][2][j]*attv[2] + acc[r][3][j]*attv[3];
      p += __shfl_xor(p, 1, 64);
      p += __shfl_xor(p, 2, 64);
      p += __shfl_xor(p, 4, 64);
      p += __shfl_xor(p, 8, 64);
      if (l15 == 0){
        float lg = p > 0.f ? p : 0.2f*p;
        alpha[(size_t)(rowb + j)*4 + head] = lg;
      }
    }
  }
}

// ---- layer-0 GAT message: reads bf16 xl + leaky'd alpha, writes single-bf16 g0 ----
__global__ __launch_bounds__(128) void gat_msg0(
    const ushort_t* __restrict__ xlhi_b, const float* __restrict__ alpha_b,
    const int* __restrict__ esrc_b, const float* __restrict__ bias_b,
    uint32_t* __restrict__ g0_u)
{
  int i = blockIdx.y, d = blockIdx.x, t = threadIdx.x;
  const ushort_t* xl = xlhi_b + (size_t)i*N0*HD;
  const float* alpha = alpha_b + (size_t)i*N0*4;
  const float* bias = bias_b + i*HD;
  __shared__ int src[16];
  __shared__ float aw[16][4];
  if (t < 16) src[t] = esrc_b[(size_t)i*E0 + d*16 + t];
  __syncthreads();
  if (t < 64){
    int e = t&15, h = t>>4;
    float l = alpha[(size_t)src[e]*4 + h];
    float m = l;
#pragma unroll
    for (int off=1; off<16; off<<=1) m = fmaxf(m, __shfl_xor(m, off, 64));
    float ex = expf(l - m);
    float s = ex;
#pragma unroll
    for (int off=1; off<16; off<<=1) s += __shfl_xor(s, off, 64);
    aw[e][h] = ex / (s + 1e-16f);
  }
  __syncthreads();
  int h = t >> 5;
  float a0=0.f, a1=0.f;
#pragma unroll
  for (int e=0;e<16;e++){
    uint32_t u = *reinterpret_cast<const uint32_t*>(xl + (size_t)src[e]*HD + 2*t);
    float w = aw[e][h];
    a0 = fmaf(w, bf2f((ushort_t)(u & 0xffffu)), a0);
    a1 = fmaf(w, bf2f((ushort_t)(u >> 16)), a1);
  }
  float v0 = a0 + bias[2*t], v1 = a1 + bias[2*t+1];
  g0_u[((size_t)i*N1 + d)*128 + t] = (uint32_t)f2bf(v0) | ((uint32_t)f2bf(v1)<<16);
}

// ---- layer-1 GAT message: fused gate + accumulate over modalities -> xmod fp32 ----
__global__ __launch_bounds__(128) void gat_msg1(
    const ushort_t* __restrict__ xl1hi, const float* __restrict__ alpha1,
    const int* __restrict__ e1src, const float* __restrict__ gat_b,
    const uint32_t* __restrict__ g0_u, const float* __restrict__ coef,
    float* __restrict__ xmod)
{
  int d = blockIdx.x, t = threadIdx.x;
  __shared__ int src[16];
  __shared__ float aw[16][4];
  float o0 = 0.f, o1 = 0.f;
  for (int i=0;i<NM;i++){
    if (t < 16) src[t] = e1src[(size_t)i*E1 + d*16 + t];
    __syncthreads();
    if (t < 64){
      int e = t&15, h = t>>4;
      float l = alpha1[((size_t)i*N1 + src[e])*4 + h];
      float m = l;
#pragma unroll
      for (int off=1; off<16; off<<=1) m = fmaxf(m, __shfl_xor(m, off, 64));
      float ex = expf(l - m);
      float s = ex;
#pragma unroll
      for (int off=1; off<16; off<<=1) s += __shfl_xor(s, off, 64);
      aw[e][h] = ex / (s + 1e-16f);
    }
    __syncthreads();
    const ushort_t* xl = xl1hi + (size_t)i*N1*HD;
    int h = t >> 5;
    float a0=0.f, a1=0.f;
#pragma unroll
    for (int e=0;e<16;e++){
      uint32_t u = *reinterpret_cast<const uint32_t*>(xl + (size_t)src[e]*HD + 2*t);
      float w = aw[e][h];
      a0 = fmaf(w, bf2f((ushort_t)(u & 0xffffu)), a0);
      a1 = fmaf(w, bf2f((ushort_t)(u >> 16)), a1);
    }
    uint32_t gh = g0_u[((size_t)i*N1 + d)*128 + t];
    float g00 = bf2f((ushort_t)(gh & 0xffffu));
    float g01 = bf2f((ushort_t)(gh >> 16));
    const float* bias = gat_b + i*HD;
    float cv = coef[d*3 + i];
    o0 += cv*(2.f*g00 + 2.f*(a0 + bias[2*t]));
    o1 += cv*(2.f*g01 + 2.f*(a1 + bias[2*t+1]));
    __syncthreads();
  }
  *reinterpret_cast<float2*>(&xmod[(size_t)d*HD + 2*t]) = make_float2(o0, o1);
}

// ---- emb_W transpose [128,256]->[256,128] ----
__global__ void transp_embW(const float* __restrict__ w, float* __restrict__ wt)
{
  int g = blockIdx.x*256 + threadIdx.x;
  int j = g >> 8, k = g & 255;
  wt[k*128 + j] = w[g];
}

// ---- emb = xmod @ embW^T + b; writes fp32 + hi/lo bf16 ----
__global__ __launch_bounds__(256) void emb_gemm(
  const float* __restrict__ xmod, const float* __restrict__ wT,
  const float* __restrict__ eb, float* __restrict__ emb,
  ushort_t* __restrict__ ehi, ushort_t* __restrict__ elo)
{
  __shared__ float xs[32][260];
  int t = threadIdx.x;
  int brow = blockIdx.x * 32;
#pragma unroll
  for (int j=0;j<8;j++){
    int linear = j*256+t;
    int row = linear >> 6;
    int kq = linear & 63;
    float4 f = *reinterpret_cast<const float4*>(&xmod[(size_t)(brow+row)*256 + kq*4]);
    xs[row][kq*4+0]=f.x; xs[row][kq*4+1]=f.y; xs[row][kq*4+2]=f.z; xs[row][kq*4+3]=f.w;
  }
  __syncthreads();
  int tj = t & 127, th = t >> 7;
  float acc[16];
#pragma unroll
  for(int r=0;r<16;r++) acc[r]=0.f;
  for (int k=0;k<256;k++){
    float w = wT[k*128 + tj];
#pragma unroll
    for (int r=0;r<16;r++) acc[r] = fmaf(xs[th*16+r][k], w, acc[r]);
  }
  float bias = eb[tj];
#pragma unroll
  for (int r=0;r<16;r++){
    size_t idx = (size_t)(brow+th*16+r)*128 + tj;
    float v = acc[r] + bias;
    emb[idx] = v;
    ushort_t hb = f2bf(v);
    ehi[idx] = hb;
    elo[idx] = f2bf(v - bf2f(hb));
  }
}

// ---- dot = emb @ emb^T via MFMA, 3-term split ----
__global__ __launch_bounds__(256) void dot_mfma(
    const ushort_t* __restrict__ Ehi, const ushort_t* __restrict__ Elo,
    float* __restrict__ dot)
{
  __shared__ __align__(16) ushort_t lb[2][16384];
  int t = threadIdx.x, wave = t>>6, lane = t&63;
  int arow0 = blockIdx.y*128, brow0 = blockIdx.x*128;
  {
    const ushort_t* srcp = (t<128) ? Ehi : Elo;
    ushort_t* dstb = lb[(t<128)?0:1];
    int o = t & 127;
    const ushort_t* rp = srcp + (size_t)(brow0+o)*128;
#pragma unroll
    for (int g=0; g<16; g++){
      short8v v = *reinterpret_cast<const short8v*>(rp + g*8);
      int c = g>>2, grp = g&3;
      int lidx = c*4096 + (o>>4)*512 + ((grp<<4)|(o&15))*8;
      *reinterpret_cast<short8v*>(&dstb[lidx]) = v;
    }
  }
  __syncthreads();

  floatx4 acc[2][8];
#pragma unroll
  for (int rt=0;rt<2;rt++)
#pragma unroll
    for (int ot=0;ot<8;ot++) acc[rt][ot] = (floatx4){0.f,0.f,0.f,0.f};

  int ar0 = arow0 + wave*32 + (lane&15);
  int ar1 = ar0 + 16;
  int koff = (lane>>4)*8;
#pragma unroll
  for (int c=0;c<4;c++){
    short8v ah0 = *reinterpret_cast<const short8v*>(Ehi + (size_t)ar0*128 + c*32 + koff);
    short8v ah1 = *reinterpret_cast<const short8v*>(Ehi + (size_t)ar1*128 + c*32 + koff);
    short8v al0 = *reinterpret_cast<const short8v*>(Elo + (size_t)ar0*128 + c*32 + koff);
    short8v al1 = *reinterpret_cast<const short8v*>(Elo + (size_t)ar1*128 + c*32 + koff);
#pragma unroll
    for (int ot=0;ot<8;ot++){
      short8v bh = *reinterpret_cast<const short8v*>(&lb[0][c*4096 + ot*512 + lane*8]);
      short8v bl = *reinterpret_cast<const short8v*>(&lb[1][c*4096 + ot*512 + lane*8]);
      acc[0][ot] = __builtin_amdgcn_mfma_f32_16x16x32_bf16(ah0, bh, acc[0][ot], 0,0,0);
      acc[0][ot] = __builtin_amdgcn_mfma_f32_16x16x32_bf16(ah0, bl, acc[0][ot], 0,0,0);
      acc[0][ot] = __builtin_amdgcn_mfma_f32_16x16x32_bf16(al0, bh, acc[0][ot], 0,0,0);
      acc[1][ot] = __builtin_amdgcn_mfma_f32_16x16x32_bf16(ah1, bh, acc[1][ot], 0,0,0);
      acc[1][ot] = __builtin_amdgcn_mfma_f32_16x16x32_bf16(ah1, bl, acc[1][ot], 0,0,0);
      acc[1][ot] = __builtin_amdgcn_mfma_f32_16x16x32_bf16(al1, bh, acc[1][ot], 0,0,0);
    }
  }
#pragma unroll
  for (int rt=0;rt<2;rt++){
    int rb = arow0 + wave*32 + rt*16 + (lane>>4)*4;
#pragma unroll
    for (int r=0;r<4;r++)
#pragma unroll
      for (int ot=0;ot<8;ot++)
        dot[(size_t)(rb+r)*4096 + brow0 + ot*16 + (lane&15)] = acc[rt][ot][r];
  }
}

extern "C" void kernel_launch(void* const* d_in, const int* in_sizes, int n_in,
                              void* d_out, int out_size, void* d_ws, size_t ws_size,
                              hipStream_t stream) {
  (void)in_sizes; (void)n_in; (void)out_size; (void)ws_size;
  const float* masks   = (const float*)d_in[0];
  const int*   n_ids   = (const int*)d_in[1];
  const int*   e0_src  = (const int*)d_in[2];
  const int*   e1_src  = (const int*)d_in[4];
  const float* pre_W   = (const float*)d_in[6];
  const float* pre_b   = (const float*)d_in[7];
  const float* gat_W   = (const float*)d_in[8];
  const float* gat_att = (const float*)d_in[9];
  const float* gat_b   = (const float*)d_in[10];
  const float* sp      = (const float*)d_in[11];
  const float* emb_W   = (const float*)d_in[12];
  const float* emb_b   = (const float*)d_in[13];

  float* out = (float*)d_out;
  float* dot = out;                         // [4096*4096]
  float* emb = out + (size_t)NB*NB;         // [4096*128]
  float* scales_out = emb + (size_t)NB*128; // [3]

  char* p = (char*)d_ws;
  auto alloc = [&](size_t bytes)->char*{ char* r = p; p += (bytes + 255) & ~(size_t)255; return r; };
  ushort_t* WThi  = (ushort_t*)alloc((size_t)NM*IN_SZ*HD*2);
  ushort_t* xlhi  = (ushort_t*)alloc((size_t)NM*N0*HD*2);
  uint32_t* g0u   = (uint32_t*)alloc((size_t)NM*N1*HD*2);
  ushort_t* xl1hi = (ushort_t*)alloc((size_t)NM*N1*HD*2);
  float*    alph0 = (float*)alloc((size_t)NM*N0*4*4);
  float*    alph1 = (float*)alloc((size_t)NM*N1*4*4);
  float*    xmod  = (float*)alloc((size_t)NB*HD*4);
  float*    coef  = (float*)alloc((size_t)NB*3*4);
  float*    wT    = (float*)alloc((size_t)HD*128*4);
  ushort_t* gWhi  = (ushort_t*)alloc((size_t)NM*HD*HD*2);
  ushort_t* gWlo  = (ushort_t*)alloc((size_t)NM*HD*HD*2);
  float*    bias2 = (float*)alloc((size_t)NM*HD*4);
  ushort_t* ehi   = (ushort_t*)alloc((size_t)NB*128*2);
  ushort_t* elo   = (ushort_t*)alloc((size_t)NB*128*2);

  interp_coef_k<<<16, 256, 0, stream>>>(masks, sp, coef, scales_out);
  transp_embW<<<128, 256, 0, stream>>>(emb_W, wT);
  split_k<<<(NM*HD*HD+255)/256, 256, 0, stream>>>(gat_W, gWhi, gWlo, NM*HD*HD);
  bias_gemv_k<<<NM, 256, 0, stream>>>(pre_b, gat_W, bias2);
  transp_k<<<dim3((IN_SZ+31)/32, 8, NM), 256, 0, stream>>>(pre_W, WThi);

  gemm2<true, true><<<dim3(N0/128, 2, NM), 256, 0, stream>>>(
      WThi, (size_t)IN_SZ*HD, n_ids, N0, gWhi, gWlo, bias2,
      xlhi, (size_t)N0*HD, gat_att, alph0, (size_t)N0*4);
  gat_msg0<<<dim3(N1, NM), 128, 0, stream>>>(xlhi, alph0, e0_src, gat_b, g0u);
  gemm2<false, false><<<dim3(N1/128, 2, NM), 256, 0, stream>>>(
      (const ushort_t*)g0u, (size_t)N1*HD, nullptr, 0, gWhi, gWlo, nullptr,
      xl1hi, (size_t)N1*HD, gat_att, alph1, (size_t)N1*4);
  gat_msg1<<<NB, 128, 0, stream>>>(xl1hi, alph1, e1_src, gat_b, g0u, coef, xmod);
  emb_gemm<<<NB/32, 256, 0, stream>>>(xmod, wT, emb_b, emb, ehi, elo);
  dot_mfma<<<dim3(32,32), 256, 0, stream>>>(ehi, elo, dot);
}